// Round 1
// baseline (615.984 us; speedup 1.0000x reference)
//
#include <hip/hip_runtime.h>
#include <cmath>

#define EPS_BN 1e-5f

// ---------------------------------------------------------------------------
// Kernel 1: depthwise 3x3 conv + BN (inference) fused.
// x: [B,H,W,C] NHWC fp32. out: [B,OH,OW,C].
// stride 1: pad_lo=1 ; stride 2: pad_lo=0 (JAX SAME, in=56,k=3).
// ---------------------------------------------------------------------------
__global__ void dwconv_bn_kernel(const float* __restrict__ x,
                                 const float* __restrict__ dw,
                                 const float* __restrict__ scale,
                                 const float* __restrict__ bias,
                                 const float* __restrict__ mean,
                                 const float* __restrict__ var,
                                 float* __restrict__ out,
                                 int B, int H, int W, int C,
                                 int stride, int OH, int OW, int pad) {
    int idx = blockIdx.x * blockDim.x + threadIdx.x;
    int total = B * OH * OW * C;
    if (idx >= total) return;
    int c = idx % C;
    int t = idx / C;
    int ox = t % OW; t /= OW;
    int oy = t % OH;
    int b  = t / OH;

    float inv = rsqrtf(var[c] + EPS_BN);
    float a  = scale[c] * inv;
    float bb = bias[c] - mean[c] * a;

    float sum = 0.f;
#pragma unroll
    for (int ky = 0; ky < 3; ky++) {
        int iy = oy * stride + ky - pad;
        if (iy < 0 || iy >= H) continue;
#pragma unroll
        for (int kx = 0; kx < 3; kx++) {
            int ix = ox * stride + kx - pad;
            if (ix < 0 || ix >= W) continue;
            sum += x[((size_t)(b * H + iy) * W + ix) * C + c] * dw[(ky * 3 + kx) * C + c];
        }
    }
    out[idx] = sum * a + bb;
}

// ---------------------------------------------------------------------------
// Kernel 2: pointwise 1x1 conv = GEMM  out[M,192] = A[M,192] x W[192,192]
// BM=BN=64, BK=16, 256 threads, 4x4 microtile. M % 64 == 0 (25088 / 6272).
// ---------------------------------------------------------------------------
__global__ __launch_bounds__(256) void pw_gemm_kernel(const float* __restrict__ A,
                                                      const float* __restrict__ Wm,
                                                      float* __restrict__ out,
                                                      int M) {
    const int K = 192, N = 192;
    __shared__ float As[16][68];  // As[k][m], padded row stride 68 floats (16B-aligned)
    __shared__ float Ws[16][68];  // Ws[k][n]

    int m0 = blockIdx.x * 64;
    int n0 = blockIdx.y * 64;
    int t  = threadIdx.x;
    int tx = t & 15, ty = t >> 4;

    float acc[4][4] = {{0.f}};

    for (int k0 = 0; k0 < K; k0 += 16) {
#pragma unroll
        for (int i = 0; i < 4; i++) {   // A tile: 64 rows x 16 k
            int e = t + i * 256;
            int r = e >> 4, cc = e & 15;
            As[cc][r] = A[(size_t)(m0 + r) * K + k0 + cc];
        }
#pragma unroll
        for (int i = 0; i < 4; i++) {   // W tile: 16 k x 64 n
            int e = t + i * 256;
            int r = e >> 6, cc = e & 63;
            Ws[r][cc] = Wm[(size_t)(k0 + r) * N + n0 + cc];
        }
        __syncthreads();
#pragma unroll
        for (int kk = 0; kk < 16; kk++) {
            float4 ar = *(const float4*)&As[kk][ty * 4];
            float4 br = *(const float4*)&Ws[kk][tx * 4];
            float arr[4] = {ar.x, ar.y, ar.z, ar.w};
            float brr[4] = {br.x, br.y, br.z, br.w};
#pragma unroll
            for (int i = 0; i < 4; i++)
#pragma unroll
                for (int j = 0; j < 4; j++)
                    acc[i][j] += arr[i] * brr[j];
        }
        __syncthreads();
    }
#pragma unroll
    for (int i = 0; i < 4; i++)
#pragma unroll
        for (int j = 0; j < 4; j++)
            out[(size_t)(m0 + ty * 4 + i) * N + n0 + tx * 4 + j] = acc[i][j];
}

// ---------------------------------------------------------------------------
// Kernel 3: flash attention, fp32. One block per (q-tile of 64, head, batch).
// q: [B,3136,192] (head h occupies cols h*64..h*64+63), k/v: [B,784,192].
// Online softmax; S and P never hit HBM. Logit scale 0.125 folded into q load.
// ---------------------------------------------------------------------------
__global__ __launch_bounds__(256) void attn_kernel(const float* __restrict__ q,
                                                   const float* __restrict__ k,
                                                   const float* __restrict__ v,
                                                   float* __restrict__ out) {
    const int LQ = 3136, LK = 784, C = 192;
    int qb = blockIdx.x, h = blockIdx.y, b = blockIdx.z;

    __shared__ float qs_t[64][68];   // [d][r]  (transposed: float4 inner reads)
    __shared__ float ks_t[64][68];   // [d][j]
    __shared__ float vs[64][68];     // [j][d]
    __shared__ float ps[64][68];     // [r][j]
    __shared__ float redm[64][17];
    __shared__ float redl[64][17];

    int t  = threadIdx.x;
    int tx = t & 15, ty = t >> 4;

    const float* qbase = q + ((size_t)b * LQ + qb * 64) * C + h * 64;
    const float* kbase = k + (size_t)b * LK * C + h * 64;
    const float* vbase = v + (size_t)b * LK * C + h * 64;

#pragma unroll
    for (int i = 0; i < 16; i++) {         // load q tile, scaled
        int e = t + i * 256;               // 0..4095
        int r = e >> 6, d = e & 63;
        qs_t[d][r] = qbase[(size_t)r * C + d] * 0.125f;
    }

    float m_run[4], l_run[4], o_acc[4][4];
#pragma unroll
    for (int i = 0; i < 4; i++) {
        m_run[i] = -INFINITY; l_run[i] = 0.f;
#pragma unroll
        for (int j = 0; j < 4; j++) o_acc[i][j] = 0.f;
    }

    for (int j0 = 0; j0 < LK; j0 += 64) {
        __syncthreads();                    // protect ks/vs from prior iter readers
#pragma unroll
        for (int i = 0; i < 16; i++) {
            int e = t + i * 256;
            int r = e >> 6, d = e & 63;
            int jg = j0 + r;
            float kv = (jg < LK) ? kbase[(size_t)jg * C + d] : 0.f;
            float vv = (jg < LK) ? vbase[(size_t)jg * C + d] : 0.f;
            ks_t[d][r] = kv;
            vs[r][d]   = vv;
        }
        __syncthreads();

        // S = Q K^T  (4x4 microtile per thread)
        float s[4][4];
#pragma unroll
        for (int i = 0; i < 4; i++)
#pragma unroll
            for (int j = 0; j < 4; j++) s[i][j] = 0.f;

        for (int d = 0; d < 64; d++) {
            float4 ar = *(const float4*)&qs_t[d][ty * 4];
            float4 br = *(const float4*)&ks_t[d][tx * 4];
            float arr[4] = {ar.x, ar.y, ar.z, ar.w};
            float brr[4] = {br.x, br.y, br.z, br.w};
#pragma unroll
            for (int i = 0; i < 4; i++)
#pragma unroll
                for (int j = 0; j < 4; j++)
                    s[i][j] += arr[i] * brr[j];
        }

        // mask out-of-range keys (last chunk: only 16 of 64 valid)
#pragma unroll
        for (int j = 0; j < 4; j++) {
            if (j0 + tx * 4 + j >= LK) {
#pragma unroll
                for (int i = 0; i < 4; i++) s[i][j] = -INFINITY;
            }
        }

        // row-max partials across the 16 tx threads
#pragma unroll
        for (int i = 0; i < 4; i++) {
            float lm = fmaxf(fmaxf(s[i][0], s[i][1]), fmaxf(s[i][2], s[i][3]));
            redm[ty * 4 + i][tx] = lm;
        }
        __syncthreads();

        float m_new[4], alpha[4];
#pragma unroll
        for (int i = 0; i < 4; i++) {
            float mm = m_run[i];
            for (int x2 = 0; x2 < 16; x2++) mm = fmaxf(mm, redm[ty * 4 + i][x2]);
            m_new[i] = mm;
            alpha[i] = __expf(m_run[i] - mm);   // first chunk: exp(-inf)=0
        }

        // P = exp(S - m_new), write to LDS, partial row sums
#pragma unroll
        for (int i = 0; i < 4; i++) {
            float lsum = 0.f;
#pragma unroll
            for (int j = 0; j < 4; j++) {
                float p = __expf(s[i][j] - m_new[i]);
                ps[ty * 4 + i][tx * 4 + j] = p;
                lsum += p;
            }
            redl[ty * 4 + i][tx] = lsum;
        }
        __syncthreads();

#pragma unroll
        for (int i = 0; i < 4; i++) {
            float cs = 0.f;
            for (int x2 = 0; x2 < 16; x2++) cs += redl[ty * 4 + i][x2];
            l_run[i] = l_run[i] * alpha[i] + cs;
            m_run[i] = m_new[i];
#pragma unroll
            for (int j = 0; j < 4; j++) o_acc[i][j] *= alpha[i];
        }

        // O += P V
        for (int j = 0; j < 64; j++) {
            float4 vr4 = *(const float4*)&vs[j][tx * 4];
            float vr[4] = {vr4.x, vr4.y, vr4.z, vr4.w};
            float pr[4];
#pragma unroll
            for (int i = 0; i < 4; i++) pr[i] = ps[ty * 4 + i][j];
#pragma unroll
            for (int i = 0; i < 4; i++)
#pragma unroll
                for (int c2 = 0; c2 < 4; c2++)
                    o_acc[i][c2] += pr[i] * vr[c2];
        }
    }

    float* obase = out + ((size_t)b * LQ + qb * 64) * C + h * 64;
#pragma unroll
    for (int i = 0; i < 4; i++) {
        float invl = 1.f / l_run[i];
#pragma unroll
        for (int j = 0; j < 4; j++)
            obase[(size_t)(ty * 4 + i) * C + tx * 4 + j] = o_acc[i][j] * invl;
    }
}

// ---------------------------------------------------------------------------
extern "C" void kernel_launch(void* const* d_in, const int* in_sizes, int n_in,
                              void* d_out, int out_size, void* d_ws, size_t ws_size,
                              hipStream_t stream) {
    const float* x = (const float*)d_in[0];

    const float* q_dw = (const float*)d_in[1];
    const float* q_scale = (const float*)d_in[2];
    const float* q_bias = (const float*)d_in[3];
    const float* q_mean = (const float*)d_in[4];
    const float* q_var = (const float*)d_in[5];
    const float* q_pw = (const float*)d_in[6];

    const float* k_dw = (const float*)d_in[7];
    const float* k_scale = (const float*)d_in[8];
    const float* k_bias = (const float*)d_in[9];
    const float* k_mean = (const float*)d_in[10];
    const float* k_var = (const float*)d_in[11];
    const float* k_pw = (const float*)d_in[12];

    const float* v_dw = (const float*)d_in[13];
    const float* v_scale = (const float*)d_in[14];
    const float* v_bias = (const float*)d_in[15];
    const float* v_mean = (const float*)d_in[16];
    const float* v_var = (const float*)d_in[17];
    const float* v_pw = (const float*)d_in[18];

    float* out = (float*)d_out;

    const int B = 8, C = 192;
    const int Mq = B * 56 * 56;   // 25088
    const int Mkv = B * 28 * 28;  // 6272

    // workspace layout (floats)
    float* ws = (float*)d_ws;
    float* h_q  = ws;                         // 25088*192 = 4,816,896
    float* qbuf = ws + 4816896;               // 4,816,896
    float* h_kv = ws + 9633792;               // 6272*192 = 1,204,224
    float* kbuf = ws + 10838016;              // 1,204,224
    float* vbuf = ws + 12042240;              // 1,204,224   (end: 13,246,464 floats = 53 MB)

    const int TPB = 256;

    // Q path: dwconv stride1 (pad 1) -> GEMM
    dwconv_bn_kernel<<<(Mq * C + TPB - 1) / TPB, TPB, 0, stream>>>(
        x, q_dw, q_scale, q_bias, q_mean, q_var, h_q, B, 56, 56, C, 1, 56, 56, 1);
    pw_gemm_kernel<<<dim3(Mq / 64, 3), TPB, 0, stream>>>(h_q, q_pw, qbuf, Mq);

    // K path: dwconv stride2 (pad 0) -> GEMM
    dwconv_bn_kernel<<<(Mkv * C + TPB - 1) / TPB, TPB, 0, stream>>>(
        x, k_dw, k_scale, k_bias, k_mean, k_var, h_kv, B, 56, 56, C, 2, 28, 28, 0);
    pw_gemm_kernel<<<dim3(Mkv / 64, 3), TPB, 0, stream>>>(h_kv, k_pw, kbuf, Mkv);

    // V path (reuses h_kv; stream-ordered after K's GEMM)
    dwconv_bn_kernel<<<(Mkv * C + TPB - 1) / TPB, TPB, 0, stream>>>(
        x, v_dw, v_scale, v_bias, v_mean, v_var, h_kv, B, 56, 56, C, 2, 28, 28, 0);
    pw_gemm_kernel<<<dim3(Mkv / 64, 3), TPB, 0, stream>>>(h_kv, v_pw, vbuf, Mkv);

    // attention: grid (49 q-tiles, 3 heads, 8 batches)
    attn_kernel<<<dim3(3136 / 64, 3, B), TPB, 0, stream>>>(qbuf, kbuf, vbuf, out);
}

// Round 2
// 308.377 us; speedup vs baseline: 1.9975x; 1.9975x over previous
//
#include <hip/hip_runtime.h>
#include <cmath>

#define EPS_BN 1e-5f

typedef __bf16 bf16;
typedef __bf16 bf16x8 __attribute__((ext_vector_type(8)));
typedef float  f32x4  __attribute__((ext_vector_type(4)));

// ---------------------------------------------------------------------------
// Kernel 1: depthwise 3x3 conv + BN (inference) fused. (unchanged from R0)
// ---------------------------------------------------------------------------
__global__ void dwconv_bn_kernel(const float* __restrict__ x,
                                 const float* __restrict__ dw,
                                 const float* __restrict__ scale,
                                 const float* __restrict__ bias,
                                 const float* __restrict__ mean,
                                 const float* __restrict__ var,
                                 float* __restrict__ out,
                                 int B, int H, int W, int C,
                                 int stride, int OH, int OW, int pad) {
    int idx = blockIdx.x * blockDim.x + threadIdx.x;
    int total = B * OH * OW * C;
    if (idx >= total) return;
    int c = idx % C;
    int t = idx / C;
    int ox = t % OW; t /= OW;
    int oy = t % OH;
    int b  = t / OH;

    float inv = rsqrtf(var[c] + EPS_BN);
    float a  = scale[c] * inv;
    float bb = bias[c] - mean[c] * a;

    float sum = 0.f;
#pragma unroll
    for (int ky = 0; ky < 3; ky++) {
        int iy = oy * stride + ky - pad;
        if (iy < 0 || iy >= H) continue;
#pragma unroll
        for (int kx = 0; kx < 3; kx++) {
            int ix = ox * stride + kx - pad;
            if (ix < 0 || ix >= W) continue;
            sum += x[((size_t)(b * H + iy) * W + ix) * C + c] * dw[(ky * 3 + kx) * C + c];
        }
    }
    out[idx] = sum * a + bb;
}

// ---------------------------------------------------------------------------
// Kernel 2: pointwise GEMM out[M,192] = A[M,192] x W[192,192], fp32 core.
// EPI 0: q -> bf16 [M,192] scaled by 0.125
// EPI 1: k -> bf16 [M,192]
// EPI 2: v -> bf16 transposed [b][h][64][784]
// ---------------------------------------------------------------------------
template <int EPI>
__global__ __launch_bounds__(256) void pw_gemm_epi(const float* __restrict__ A,
                                                   const float* __restrict__ Wm,
                                                   void* __restrict__ outp,
                                                   int M) {
    const int K = 192, N = 192;
    __shared__ float As[16][68];
    __shared__ float Ws[16][68];

    int m0 = blockIdx.x * 64;
    int n0 = blockIdx.y * 64;
    int t  = threadIdx.x;
    int tx = t & 15, ty = t >> 4;

    float acc[4][4] = {{0.f}};

    for (int k0 = 0; k0 < K; k0 += 16) {
#pragma unroll
        for (int i = 0; i < 4; i++) {
            int e = t + i * 256;
            int r = e >> 4, cc = e & 15;
            As[cc][r] = A[(size_t)(m0 + r) * K + k0 + cc];
        }
#pragma unroll
        for (int i = 0; i < 4; i++) {
            int e = t + i * 256;
            int r = e >> 6, cc = e & 63;
            Ws[r][cc] = Wm[(size_t)(k0 + r) * N + n0 + cc];
        }
        __syncthreads();
#pragma unroll
        for (int kk = 0; kk < 16; kk++) {
            float4 ar = *(const float4*)&As[kk][ty * 4];
            float4 br = *(const float4*)&Ws[kk][tx * 4];
            float arr[4] = {ar.x, ar.y, ar.z, ar.w};
            float brr[4] = {br.x, br.y, br.z, br.w};
#pragma unroll
            for (int i = 0; i < 4; i++)
#pragma unroll
                for (int j = 0; j < 4; j++)
                    acc[i][j] += arr[i] * brr[j];
        }
        __syncthreads();
    }

    if (EPI == 0) {
        bf16* o = (bf16*)outp;
#pragma unroll
        for (int i = 0; i < 4; i++)
#pragma unroll
            for (int j = 0; j < 4; j++)
                o[(size_t)(m0 + ty * 4 + i) * N + n0 + tx * 4 + j] = (bf16)(acc[i][j] * 0.125f);
    } else if (EPI == 1) {
        bf16* o = (bf16*)outp;
#pragma unroll
        for (int i = 0; i < 4; i++)
#pragma unroll
            for (int j = 0; j < 4; j++)
                o[(size_t)(m0 + ty * 4 + i) * N + n0 + tx * 4 + j] = (bf16)acc[i][j];
    } else {
        bf16* o = (bf16*)outp;  // [b][h][64 d][784 loc]
#pragma unroll
        for (int i = 0; i < 4; i++) {
            int gm = m0 + ty * 4 + i;
            int bb = gm / 784;
            int loc = gm - bb * 784;
#pragma unroll
            for (int j = 0; j < 4; j++) {
                int gn = n0 + tx * 4 + j;
                int hh = gn >> 6, d = gn & 63;
                o[(((size_t)bb * 3 + hh) * 64 + d) * 784 + loc] = (bf16)acc[i][j];
            }
        }
    }
}

// ---------------------------------------------------------------------------
// Kernel 3: flash attention with bf16 MFMA (16x16x32).
// Block = 64 q-rows x (head, batch). 4 waves, 16 rows each. BK = 64.
// q: [B,3136,192] bf16 (pre-scaled by 0.125), k: [B,784,192] bf16,
// vt: [b][h][64][784] bf16, out: [B,3136,192] fp32.
// LDS rows padded to 72 bf16 (144 B) -> 2-way bank alias only (free).
// ---------------------------------------------------------------------------
__global__ __launch_bounds__(256) void attn_mfma_kernel(const bf16* __restrict__ qb,
                                                        const bf16* __restrict__ kb,
                                                        const bf16* __restrict__ vtb,
                                                        float* __restrict__ out) {
    const int LQ = 3136, LK = 784, C = 192, H = 3;
    int qt = blockIdx.x, h = blockIdx.y, b = blockIdx.z;

    __shared__ bf16 Qs[64][72];
    __shared__ bf16 Ks[64][72];
    __shared__ bf16 Vts[64][72];   // [d][j]
    __shared__ bf16 Ps[64][72];    // [q][j]

    int t    = threadIdx.x;
    int lane = t & 63;
    int wid  = t >> 6;
    int l16  = lane & 15;
    int quad = lane >> 4;
    int wrow = wid * 16;

    // stage Q tile (64 x 64 bf16), 16 B per lane, 2 iters
    {
        const bf16* qbase = qb + ((size_t)b * LQ + qt * 64) * C + h * 64;
#pragma unroll
        for (int it = 0; it < 2; it++) {
            int e = t + it * 256;
            int r = e >> 3, s = e & 7;
            uint4 val = *(const uint4*)(qbase + (size_t)r * C + s * 8);
            *(uint4*)&Qs[r][s * 8] = val;
        }
    }

    float m_run[4], l_run[4];
    f32x4 o_acc[4];
#pragma unroll
    for (int i = 0; i < 4; i++) {
        m_run[i] = -INFINITY;
        l_run[i] = 0.f;
        o_acc[i] = f32x4{0.f, 0.f, 0.f, 0.f};
    }

    const bf16* kbase  = kb + (size_t)b * LK * C + h * 64;
    const bf16* vtbase = vtb + ((size_t)(b * H + h)) * 64 * LK;

    for (int j0 = 0; j0 < LK; j0 += 64) {
        __syncthreads();
        // stage K chunk [64 keys][64 d]
#pragma unroll
        for (int it = 0; it < 2; it++) {
            int e = t + it * 256;
            int r = e >> 3, s = e & 7;
            int jg = j0 + r;
            uint4 val = make_uint4(0u, 0u, 0u, 0u);
            if (jg < LK) val = *(const uint4*)(kbase + (size_t)jg * C + s * 8);
            *(uint4*)&Ks[r][s * 8] = val;
        }
        // stage Vt chunk [64 d][64 j]
#pragma unroll
        for (int it = 0; it < 2; it++) {
            int e = t + it * 256;
            int r = e >> 3, s = e & 7;
            uint4 val = make_uint4(0u, 0u, 0u, 0u);
            if (j0 + s * 8 < LK) val = *(const uint4*)(vtbase + (size_t)r * LK + j0 + s * 8);
            *(uint4*)&Vts[r][s * 8] = val;
        }
        __syncthreads();

        // S = Q K^T : rows = wave's 16 q, cols = 64 keys (4 n-tiles), K-dim 64 (2 steps)
        f32x4 s_acc[4];
#pragma unroll
        for (int n = 0; n < 4; n++) s_acc[n] = f32x4{0.f, 0.f, 0.f, 0.f};
#pragma unroll
        for (int kk = 0; kk < 2; kk++) {
            bf16x8 afrag = *(const bf16x8*)&Qs[wrow + l16][kk * 32 + quad * 8];
#pragma unroll
            for (int n = 0; n < 4; n++) {
                bf16x8 bfrag = *(const bf16x8*)&Ks[n * 16 + l16][kk * 32 + quad * 8];
                s_acc[n] = __builtin_amdgcn_mfma_f32_16x16x32_bf16(afrag, bfrag, s_acc[n], 0, 0, 0);
            }
        }

        // mask invalid keys, row max (C layout: row = quad*4+reg, col = n*16+l16)
        float rowmax[4];
#pragma unroll
        for (int reg = 0; reg < 4; reg++) {
            float mx = -INFINITY;
#pragma unroll
            for (int n = 0; n < 4; n++) {
                float sv = s_acc[n][reg];
                int j = j0 + n * 16 + l16;
                sv = (j < LK) ? sv : -INFINITY;
                s_acc[n][reg] = sv;
                mx = fmaxf(mx, sv);
            }
            rowmax[reg] = mx;
        }
#pragma unroll
        for (int m = 1; m < 16; m <<= 1)
#pragma unroll
            for (int reg = 0; reg < 4; reg++)
                rowmax[reg] = fmaxf(rowmax[reg], __shfl_xor(rowmax[reg], m, 64));

        float m_new[4], alpha[4], rowsum[4];
#pragma unroll
        for (int reg = 0; reg < 4; reg++) {
            m_new[reg] = fmaxf(m_run[reg], rowmax[reg]);
            alpha[reg] = __expf(m_run[reg] - m_new[reg]);  // first chunk: exp(-inf)=0
            float rs = 0.f;
#pragma unroll
            for (int n = 0; n < 4; n++) {
                float p = __expf(s_acc[n][reg] - m_new[reg]);
                rs += p;
                Ps[wrow + quad * 4 + reg][n * 16 + l16] = (bf16)p;
            }
            rowsum[reg] = rs;
        }
#pragma unroll
        for (int m = 1; m < 16; m <<= 1)
#pragma unroll
            for (int reg = 0; reg < 4; reg++)
                rowsum[reg] += __shfl_xor(rowsum[reg], m, 64);
#pragma unroll
        for (int reg = 0; reg < 4; reg++) {
            l_run[reg] = l_run[reg] * alpha[reg] + rowsum[reg];
            m_run[reg] = m_new[reg];
        }
#pragma unroll
        for (int n = 0; n < 4; n++)
#pragma unroll
            for (int reg = 0; reg < 4; reg++)
                o_acc[n][reg] *= alpha[reg];

        // O += P Vt^T (wave-local Ps rows; no barrier needed)
#pragma unroll
        for (int kk = 0; kk < 2; kk++) {
            bf16x8 pfrag = *(const bf16x8*)&Ps[wrow + l16][kk * 32 + quad * 8];
#pragma unroll
            for (int n = 0; n < 4; n++) {
                bf16x8 vfrag = *(const bf16x8*)&Vts[n * 16 + l16][kk * 32 + quad * 8];
                o_acc[n] = __builtin_amdgcn_mfma_f32_16x16x32_bf16(pfrag, vfrag, o_acc[n], 0, 0, 0);
            }
        }
    }

    // epilogue: out[q][d] fp32, rows contiguous in 16-float runs
    float* obase = out + ((size_t)b * LQ + qt * 64 + wrow) * C + h * 64;
#pragma unroll
    for (int reg = 0; reg < 4; reg++) {
        float invl = 1.f / l_run[reg];
#pragma unroll
        for (int n = 0; n < 4; n++)
            obase[(size_t)(quad * 4 + reg) * C + n * 16 + l16] = o_acc[n][reg] * invl;
    }
}

// ---------------------------------------------------------------------------
extern "C" void kernel_launch(void* const* d_in, const int* in_sizes, int n_in,
                              void* d_out, int out_size, void* d_ws, size_t ws_size,
                              hipStream_t stream) {
    const float* x = (const float*)d_in[0];

    const float* q_dw = (const float*)d_in[1];
    const float* q_scale = (const float*)d_in[2];
    const float* q_bias = (const float*)d_in[3];
    const float* q_mean = (const float*)d_in[4];
    const float* q_var = (const float*)d_in[5];
    const float* q_pw = (const float*)d_in[6];

    const float* k_dw = (const float*)d_in[7];
    const float* k_scale = (const float*)d_in[8];
    const float* k_bias = (const float*)d_in[9];
    const float* k_mean = (const float*)d_in[10];
    const float* k_var = (const float*)d_in[11];
    const float* k_pw = (const float*)d_in[12];

    const float* v_dw = (const float*)d_in[13];
    const float* v_scale = (const float*)d_in[14];
    const float* v_bias = (const float*)d_in[15];
    const float* v_mean = (const float*)d_in[16];
    const float* v_var = (const float*)d_in[17];
    const float* v_pw = (const float*)d_in[18];

    float* out = (float*)d_out;

    const int B = 8, C = 192;
    const int Mq = B * 56 * 56;   // 25088
    const int Mkv = B * 28 * 28;  // 6272

    // workspace layout (bytes)
    char* ws = (char*)d_ws;
    float* h_q  = (float*)(ws);                     // 4,816,896 f32
    float* h_kv = (float*)(ws + 19267584);          // 1,204,224 f32
    bf16*  qbuf = (bf16*)(ws + 24084480);           // 4,816,896 bf16
    bf16*  kbuf = (bf16*)(ws + 33718272);           // 1,204,224 bf16
    bf16*  vtbuf= (bf16*)(ws + 36126720);           // 1,204,224 bf16 (end 38,535,168)

    const int TPB = 256;

    // Q path: dwconv stride1 (pad 1) -> GEMM -> bf16 (x0.125)
    dwconv_bn_kernel<<<(Mq * C + TPB - 1) / TPB, TPB, 0, stream>>>(
        x, q_dw, q_scale, q_bias, q_mean, q_var, h_q, B, 56, 56, C, 1, 56, 56, 1);
    pw_gemm_epi<0><<<dim3(Mq / 64, 3), TPB, 0, stream>>>(h_q, q_pw, qbuf, Mq);

    // K path: dwconv stride2 (pad 0) -> GEMM -> bf16
    dwconv_bn_kernel<<<(Mkv * C + TPB - 1) / TPB, TPB, 0, stream>>>(
        x, k_dw, k_scale, k_bias, k_mean, k_var, h_kv, B, 56, 56, C, 2, 28, 28, 0);
    pw_gemm_epi<1><<<dim3(Mkv / 64, 3), TPB, 0, stream>>>(h_kv, k_pw, kbuf, Mkv);

    // V path (reuses h_kv; stream-ordered after K's GEMM) -> bf16 transposed
    dwconv_bn_kernel<<<(Mkv * C + TPB - 1) / TPB, TPB, 0, stream>>>(
        x, v_dw, v_scale, v_bias, v_mean, v_var, h_kv, B, 56, 56, C, 2, 28, 28, 0);
    pw_gemm_epi<2><<<dim3(Mkv / 64, 3), TPB, 0, stream>>>(h_kv, v_pw, vtbuf, Mkv);

    // attention: grid (49 q-tiles, 3 heads, 8 batches)
    attn_mfma_kernel<<<dim3(3136 / 64, 3, B), TPB, 0, stream>>>(qbuf, kbuf, vtbuf, out);
}

// Round 3
// 294.194 us; speedup vs baseline: 2.0938x; 1.0482x over previous
//
#include <hip/hip_runtime.h>
#include <cmath>

#define EPS_BN 1e-5f

typedef __bf16 bf16;
typedef __bf16 bf16x4 __attribute__((ext_vector_type(4)));
typedef __bf16 bf16x8 __attribute__((ext_vector_type(8)));
typedef float  f32x4  __attribute__((ext_vector_type(4)));

// ---------------------------------------------------------------------------
// Kernel 0: cast + transpose the three 1x1 conv weights to bf16 Wt[n][k].
// src pw is [k_in=192][n_out=192] row-major; wt[mat][n][k] = pw[k][n].
// ---------------------------------------------------------------------------
__global__ void cast_w_kernel(const float* __restrict__ qpw,
                              const float* __restrict__ kpw,
                              const float* __restrict__ vpw,
                              bf16* __restrict__ wt) {
    int idx = blockIdx.x * 256 + threadIdx.x;
    if (idx >= 3 * 36864) return;
    int mat = idx / 36864, r = idx % 36864;
    int n = r / 192, k = r - n * 192;
    const float* src = (mat == 0) ? qpw : (mat == 1) ? kpw : vpw;
    wt[idx] = (bf16)src[k * 192 + n];
}

// ---------------------------------------------------------------------------
// Kernel 1: fused dwconv3x3 + BN + pointwise GEMM (bf16 MFMA, split-hi/lo A).
// Block = 64 output positions x all 192 out-channels. 256 threads, 4 waves.
// EPI 0: q -> bf16 [M,192] * 0.125 ; EPI 1: k -> bf16 [M,192]
// EPI 2: v -> bf16 transposed [b*3+h][64 d][784 loc]
// ---------------------------------------------------------------------------
template <int STRIDE, int PAD, int EPI>
__global__ __launch_bounds__(256) void fused_proj_kernel(
    const float* __restrict__ x,
    const float* __restrict__ dw, const float* __restrict__ scale,
    const float* __restrict__ bias, const float* __restrict__ mean,
    const float* __restrict__ var,
    const bf16* __restrict__ Wt,      // [192 n][192 k]
    bf16* __restrict__ outp) {
    const int HH = 56, WW = 56, C = 192;
    const int OW = WW / STRIDE, Mper = OW * OW;

    __shared__ bf16 Ahi[64][200];     // [pos][k], pad 8 -> 16B-aligned rows
    __shared__ bf16 Alo[64][200];
    __shared__ bf16 Wtile[192][40];   // [n][k-chunk 32], pad 8
    __shared__ float dwS[9][192];     // BN-folded taps
    __shared__ float bbS[192];

    int t = threadIdx.x;
    int m0 = blockIdx.x * 64;

    // phase 0: fold BN into taps
    for (int c = t; c < 192; c += 256) {
        float a = scale[c] * rsqrtf(var[c] + EPS_BN);
        bbS[c] = bias[c] - mean[c] * a;
#pragma unroll
        for (int tap = 0; tap < 9; tap++)
            dwS[tap][c] = dw[tap * 192 + c] * a;
    }
    __syncthreads();

    // phase 1: depthwise conv, float4 per iter, 12 iters covers 64x192
#pragma unroll
    for (int e = 0; e < 12; e++) {
        int idx4 = e * 256 + t;             // 0..3071
        int i  = idx4 / 48;                 // position row 0..63
        int c4 = (idx4 - i * 48) * 4;       // channel 0..188 step 4
        int p  = m0 + i;
        int b  = p / Mper;
        int rem = p - b * Mper;
        int oy = rem / OW;
        int ox = rem - oy * OW;
        const float* xb = x + (size_t)b * HH * WW * C;

        float4 acc4 = *(const float4*)&bbS[c4];
#pragma unroll
        for (int ky = 0; ky < 3; ky++) {
            int iy = oy * STRIDE + ky - PAD;
            bool yok = (iy >= 0) && (iy < HH);
#pragma unroll
            for (int kx = 0; kx < 3; kx++) {
                int ix = ox * STRIDE + kx - PAD;
                bool ok = yok && (ix >= 0) && (ix < WW);
                if (ok) {
                    float4 xv = *(const float4*)&xb[((size_t)iy * WW + ix) * C + c4];
                    float4 wv = *(const float4*)&dwS[ky * 3 + kx][c4];
                    acc4.x += xv.x * wv.x;
                    acc4.y += xv.y * wv.y;
                    acc4.z += xv.z * wv.z;
                    acc4.w += xv.w * wv.w;
                }
            }
        }
        // split fp32 -> hi + lo bf16
        float av[4] = {acc4.x, acc4.y, acc4.z, acc4.w};
        bf16x4 hi, lo;
#pragma unroll
        for (int j = 0; j < 4; j++) {
            bf16 h = (bf16)av[j];
            hi[j] = h;
            lo[j] = (bf16)(av[j] - (float)h);
        }
        *(bf16x4*)&Ahi[i][c4] = hi;
        *(bf16x4*)&Alo[i][c4] = lo;
    }
    __syncthreads();

    // phase 2: MFMA GEMM  out[64,192] = A[64,192] x W[192,192]
    int lane = t & 63, wid = t >> 6;
    int l16 = lane & 15, quad = lane >> 4;
    int wrow = wid * 16;

    f32x4 acc[12];
#pragma unroll
    for (int n = 0; n < 12; n++) acc[n] = f32x4{0.f, 0.f, 0.f, 0.f};

    for (int kc = 0; kc < 6; kc++) {
        // stage Wt chunk [192 n][32 k]
#pragma unroll
        for (int it = 0; it < 3; it++) {
            int idx = it * 256 + t;          // 0..767
            int n = idx >> 2, kp = idx & 3;
            *(uint4*)&Wtile[n][kp * 8] = *(const uint4*)&Wt[n * 192 + kc * 32 + kp * 8];
        }
        __syncthreads();

        bf16x8 ah = *(const bf16x8*)&Ahi[wrow + l16][kc * 32 + quad * 8];
        bf16x8 al = *(const bf16x8*)&Alo[wrow + l16][kc * 32 + quad * 8];
#pragma unroll
        for (int n = 0; n < 12; n++) {
            bf16x8 bfr = *(const bf16x8*)&Wtile[n * 16 + l16][quad * 8];
            acc[n] = __builtin_amdgcn_mfma_f32_16x16x32_bf16(al, bfr, acc[n], 0, 0, 0);
            acc[n] = __builtin_amdgcn_mfma_f32_16x16x32_bf16(ah, bfr, acc[n], 0, 0, 0);
        }
        __syncthreads();
    }

    // epilogue (C layout: row = quad*4+reg, col = n*16+l16)
    if (EPI == 2) {
#pragma unroll
        for (int reg = 0; reg < 4; reg++) {
            int row = m0 + wrow + quad * 4 + reg;
            int b = row / 784;
            int loc = row - b * 784;
#pragma unroll
            for (int n = 0; n < 12; n++) {
                int col = n * 16 + l16;
                int h = col >> 6, d = col & 63;
                outp[(((size_t)b * 3 + h) * 64 + d) * 784 + loc] = (bf16)acc[n][reg];
            }
        }
    } else {
        const float s = (EPI == 0) ? 0.125f : 1.0f;
#pragma unroll
        for (int reg = 0; reg < 4; reg++) {
            size_t row = m0 + wrow + quad * 4 + reg;
#pragma unroll
            for (int n = 0; n < 12; n++)
                outp[row * 192 + n * 16 + l16] = (bf16)(acc[n][reg] * s);
        }
    }
}

// ---------------------------------------------------------------------------
// Kernel 2: flash attention with bf16 MFMA (unchanged from R2, verified).
// ---------------------------------------------------------------------------
__global__ __launch_bounds__(256) void attn_mfma_kernel(const bf16* __restrict__ qb,
                                                        const bf16* __restrict__ kb,
                                                        const bf16* __restrict__ vtb,
                                                        float* __restrict__ out) {
    const int LQ = 3136, LK = 784, C = 192, H = 3;
    int qt = blockIdx.x, h = blockIdx.y, b = blockIdx.z;

    __shared__ bf16 Qs[64][72];
    __shared__ bf16 Ks[64][72];
    __shared__ bf16 Vts[64][72];
    __shared__ bf16 Ps[64][72];

    int t    = threadIdx.x;
    int lane = t & 63;
    int wid  = t >> 6;
    int l16  = lane & 15;
    int quad = lane >> 4;
    int wrow = wid * 16;

    {
        const bf16* qbase = qb + ((size_t)b * LQ + qt * 64) * C + h * 64;
#pragma unroll
        for (int it = 0; it < 2; it++) {
            int e = t + it * 256;
            int r = e >> 3, s = e & 7;
            uint4 val = *(const uint4*)(qbase + (size_t)r * C + s * 8);
            *(uint4*)&Qs[r][s * 8] = val;
        }
    }

    float m_run[4], l_run[4];
    f32x4 o_acc[4];
#pragma unroll
    for (int i = 0; i < 4; i++) {
        m_run[i] = -INFINITY;
        l_run[i] = 0.f;
        o_acc[i] = f32x4{0.f, 0.f, 0.f, 0.f};
    }

    const bf16* kbase  = kb + (size_t)b * LK * C + h * 64;
    const bf16* vtbase = vtb + ((size_t)(b * H + h)) * 64 * LK;

    for (int j0 = 0; j0 < LK; j0 += 64) {
        __syncthreads();
#pragma unroll
        for (int it = 0; it < 2; it++) {
            int e = t + it * 256;
            int r = e >> 3, s = e & 7;
            int jg = j0 + r;
            uint4 val = make_uint4(0u, 0u, 0u, 0u);
            if (jg < LK) val = *(const uint4*)(kbase + (size_t)jg * C + s * 8);
            *(uint4*)&Ks[r][s * 8] = val;
        }
#pragma unroll
        for (int it = 0; it < 2; it++) {
            int e = t + it * 256;
            int r = e >> 3, s = e & 7;
            uint4 val = make_uint4(0u, 0u, 0u, 0u);
            if (j0 + s * 8 < LK) val = *(const uint4*)(vtbase + (size_t)r * LK + j0 + s * 8);
            *(uint4*)&Vts[r][s * 8] = val;
        }
        __syncthreads();

        f32x4 s_acc[4];
#pragma unroll
        for (int n = 0; n < 4; n++) s_acc[n] = f32x4{0.f, 0.f, 0.f, 0.f};
#pragma unroll
        for (int kk = 0; kk < 2; kk++) {
            bf16x8 afrag = *(const bf16x8*)&Qs[wrow + l16][kk * 32 + quad * 8];
#pragma unroll
            for (int n = 0; n < 4; n++) {
                bf16x8 bfrag = *(const bf16x8*)&Ks[n * 16 + l16][kk * 32 + quad * 8];
                s_acc[n] = __builtin_amdgcn_mfma_f32_16x16x32_bf16(afrag, bfrag, s_acc[n], 0, 0, 0);
            }
        }

        float rowmax[4];
#pragma unroll
        for (int reg = 0; reg < 4; reg++) {
            float mx = -INFINITY;
#pragma unroll
            for (int n = 0; n < 4; n++) {
                float sv = s_acc[n][reg];
                int j = j0 + n * 16 + l16;
                sv = (j < LK) ? sv : -INFINITY;
                s_acc[n][reg] = sv;
                mx = fmaxf(mx, sv);
            }
            rowmax[reg] = mx;
        }
#pragma unroll
        for (int m = 1; m < 16; m <<= 1)
#pragma unroll
            for (int reg = 0; reg < 4; reg++)
                rowmax[reg] = fmaxf(rowmax[reg], __shfl_xor(rowmax[reg], m, 64));

        float m_new[4], alpha[4], rowsum[4];
#pragma unroll
        for (int reg = 0; reg < 4; reg++) {
            m_new[reg] = fmaxf(m_run[reg], rowmax[reg]);
            alpha[reg] = __expf(m_run[reg] - m_new[reg]);
            float rs = 0.f;
#pragma unroll
            for (int n = 0; n < 4; n++) {
                float p = __expf(s_acc[n][reg] - m_new[reg]);
                rs += p;
                Ps[wrow + quad * 4 + reg][n * 16 + l16] = (bf16)p;
            }
            rowsum[reg] = rs;
        }
#pragma unroll
        for (int m = 1; m < 16; m <<= 1)
#pragma unroll
            for (int reg = 0; reg < 4; reg++)
                rowsum[reg] += __shfl_xor(rowsum[reg], m, 64);
#pragma unroll
        for (int reg = 0; reg < 4; reg++) {
            l_run[reg] = l_run[reg] * alpha[reg] + rowsum[reg];
            m_run[reg] = m_new[reg];
        }
#pragma unroll
        for (int n = 0; n < 4; n++)
#pragma unroll
            for (int reg = 0; reg < 4; reg++)
                o_acc[n][reg] *= alpha[reg];

#pragma unroll
        for (int kk = 0; kk < 2; kk++) {
            bf16x8 pfrag = *(const bf16x8*)&Ps[wrow + l16][kk * 32 + quad * 8];
#pragma unroll
            for (int n = 0; n < 4; n++) {
                bf16x8 vfrag = *(const bf16x8*)&Vts[n * 16 + l16][kk * 32 + quad * 8];
                o_acc[n] = __builtin_amdgcn_mfma_f32_16x16x32_bf16(pfrag, vfrag, o_acc[n], 0, 0, 0);
            }
        }
    }

    float* obase = out + ((size_t)b * LQ + qt * 64 + wrow) * C + h * 64;
#pragma unroll
    for (int reg = 0; reg < 4; reg++) {
        float invl = 1.f / l_run[reg];
#pragma unroll
        for (int n = 0; n < 4; n++)
            obase[(size_t)(quad * 4 + reg) * C + n * 16 + l16] = o_acc[n][reg] * invl;
    }
}

// ---------------------------------------------------------------------------
extern "C" void kernel_launch(void* const* d_in, const int* in_sizes, int n_in,
                              void* d_out, int out_size, void* d_ws, size_t ws_size,
                              hipStream_t stream) {
    const float* x = (const float*)d_in[0];

    const float* q_dw = (const float*)d_in[1];
    const float* q_scale = (const float*)d_in[2];
    const float* q_bias = (const float*)d_in[3];
    const float* q_mean = (const float*)d_in[4];
    const float* q_var = (const float*)d_in[5];
    const float* q_pw = (const float*)d_in[6];

    const float* k_dw = (const float*)d_in[7];
    const float* k_scale = (const float*)d_in[8];
    const float* k_bias = (const float*)d_in[9];
    const float* k_mean = (const float*)d_in[10];
    const float* k_var = (const float*)d_in[11];
    const float* k_pw = (const float*)d_in[12];

    const float* v_dw = (const float*)d_in[13];
    const float* v_scale = (const float*)d_in[14];
    const float* v_bias = (const float*)d_in[15];
    const float* v_mean = (const float*)d_in[16];
    const float* v_var = (const float*)d_in[17];
    const float* v_pw = (const float*)d_in[18];

    float* out = (float*)d_out;

    // workspace layout (bytes)
    char* ws = (char*)d_ws;
    bf16* qbuf = (bf16*)(ws);               // 9,633,792 B
    bf16* kbuf = (bf16*)(ws + 9633792);     // 2,408,448 B
    bf16* vtbuf = (bf16*)(ws + 12042240);   // 2,408,448 B
    bf16* wt   = (bf16*)(ws + 14450688);    // 221,184 B (3 x 192 x 192)

    cast_w_kernel<<<432, 256, 0, stream>>>(q_pw, k_pw, v_pw, wt);

    // Q: stride 1, pad 1 ; grid 25088/64 = 392
    fused_proj_kernel<1, 1, 0><<<392, 256, 0, stream>>>(
        x, q_dw, q_scale, q_bias, q_mean, q_var, wt, qbuf);
    // K: stride 2, pad 0 ; grid 6272/64 = 98
    fused_proj_kernel<2, 0, 1><<<98, 256, 0, stream>>>(
        x, k_dw, k_scale, k_bias, k_mean, k_var, wt + 36864, kbuf);
    // V: stride 2, pad 0
    fused_proj_kernel<2, 0, 2><<<98, 256, 0, stream>>>(
        x, v_dw, v_scale, v_bias, v_mean, v_var, wt + 2 * 36864, vtbuf);

    // attention: grid (49 q-tiles, 3 heads, 8 batches)
    attn_mfma_kernel<<<dim3(3136 / 64, 3, 8), 256, 0, stream>>>(qbuf, kbuf, vtbuf, out);
}

// Round 4
// 233.414 us; speedup vs baseline: 2.6390x; 1.2604x over previous
//
#include <hip/hip_runtime.h>
#include <cmath>

#define EPS_BN 1e-5f

typedef __bf16 bf16;
typedef __bf16 bf16x4 __attribute__((ext_vector_type(4)));
typedef __bf16 bf16x8 __attribute__((ext_vector_type(8)));
typedef float  f32x4  __attribute__((ext_vector_type(4)));

// ---------------------------------------------------------------------------
// Kernel 0: cast + transpose the three 1x1 conv weights to bf16 Wt[n][k].
// ---------------------------------------------------------------------------
__global__ void cast_w_kernel(const float* __restrict__ qpw,
                              const float* __restrict__ kpw,
                              const float* __restrict__ vpw,
                              bf16* __restrict__ wt) {
    int idx = blockIdx.x * 256 + threadIdx.x;
    if (idx >= 3 * 36864) return;
    int mat = idx / 36864, r = idx % 36864;
    int n = r / 192, k = r - n * 192;
    const float* src = (mat == 0) ? qpw : (mat == 1) ? kpw : vpw;
    wt[idx] = (bf16)src[k * 192 + n];
}

// ---------------------------------------------------------------------------
// Kernel 1a: Q depthwise conv + BN -> hi/lo bf16. One float4-column per thread.
// stride 1, pad 1. tasks = 25088 * 48.
// ---------------------------------------------------------------------------
__global__ __launch_bounds__(256) void conv_q_kernel(
    const float* __restrict__ x,
    const float* __restrict__ dw, const float* __restrict__ scale,
    const float* __restrict__ bias, const float* __restrict__ mean,
    const float* __restrict__ var,
    bf16* __restrict__ hi_out, bf16* __restrict__ lo_out) {
    const int WW = 56, C = 192;
    int idx = blockIdx.x * 256 + threadIdx.x;       // 0 .. 25088*48-1
    int p  = idx / 48;
    int c4 = (idx - p * 48) * 4;
    int b  = p / 3136;
    int rem = p - b * 3136;
    int oy = rem / 56;
    int ox = rem - oy * 56;
    const float* xb = x + (size_t)b * 3136 * C;

    float4 sc = *(const float4*)&scale[c4];
    float4 vr = *(const float4*)&var[c4];
    float4 bi = *(const float4*)&bias[c4];
    float4 mn = *(const float4*)&mean[c4];
    float a0 = sc.x * rsqrtf(vr.x + EPS_BN);
    float a1 = sc.y * rsqrtf(vr.y + EPS_BN);
    float a2 = sc.z * rsqrtf(vr.z + EPS_BN);
    float a3 = sc.w * rsqrtf(vr.w + EPS_BN);
    float s0 = 0.f, s1 = 0.f, s2 = 0.f, s3 = 0.f;
#pragma unroll
    for (int ky = 0; ky < 3; ky++) {
        int iy = oy + ky - 1;
        bool yok = (iy >= 0) && (iy < 56);
#pragma unroll
        for (int kx = 0; kx < 3; kx++) {
            int ix = ox + kx - 1;
            if (yok && ix >= 0 && ix < WW) {
                float4 xv = *(const float4*)&xb[((size_t)iy * WW + ix) * C + c4];
                float4 wv = *(const float4*)&dw[(ky * 3 + kx) * C + c4];
                s0 += xv.x * wv.x; s1 += xv.y * wv.y;
                s2 += xv.z * wv.z; s3 += xv.w * wv.w;
            }
        }
    }
    float av[4];
    av[0] = s0 * a0 + (bi.x - mn.x * a0);
    av[1] = s1 * a1 + (bi.y - mn.y * a1);
    av[2] = s2 * a2 + (bi.z - mn.z * a2);
    av[3] = s3 * a3 + (bi.w - mn.w * a3);
    bf16x4 hv, lv;
#pragma unroll
    for (int j = 0; j < 4; j++) {
        bf16 h = (bf16)av[j];
        hv[j] = h;
        lv[j] = (bf16)(av[j] - (float)h);
    }
    *(bf16x4*)&hi_out[(size_t)p * C + c4] = hv;
    *(bf16x4*)&lo_out[(size_t)p * C + c4] = lv;
}

// ---------------------------------------------------------------------------
// Kernel 1b: K and V depthwise conv + BN -> hi/lo bf16 (shared x loads).
// stride 2, pad 0. tasks = 6272 * 48.
// ---------------------------------------------------------------------------
__global__ __launch_bounds__(256) void conv_kv_kernel(
    const float* __restrict__ x,
    const float* __restrict__ kdw, const float* __restrict__ kscale,
    const float* __restrict__ kbias, const float* __restrict__ kmean,
    const float* __restrict__ kvar,
    const float* __restrict__ vdw, const float* __restrict__ vscale,
    const float* __restrict__ vbias, const float* __restrict__ vmean,
    const float* __restrict__ vvar,
    bf16* __restrict__ khi, bf16* __restrict__ klo,
    bf16* __restrict__ vhi, bf16* __restrict__ vlo) {
    const int WW = 56, C = 192;
    int idx = blockIdx.x * 256 + threadIdx.x;       // 0 .. 6272*48-1
    int p  = idx / 48;
    int c4 = (idx - p * 48) * 4;
    int b  = p / 784;
    int rem = p - b * 784;
    int oy = rem / 28;
    int ox = rem - oy * 28;
    const float* xb = x + (size_t)b * 3136 * C;

    float ks[4] = {0.f, 0.f, 0.f, 0.f};
    float vs[4] = {0.f, 0.f, 0.f, 0.f};
#pragma unroll
    for (int ky = 0; ky < 3; ky++) {
        int iy = oy * 2 + ky;
        bool yok = iy < 56;
#pragma unroll
        for (int kx = 0; kx < 3; kx++) {
            int ix = ox * 2 + kx;
            if (yok && ix < WW) {
                float4 xv = *(const float4*)&xb[((size_t)iy * WW + ix) * C + c4];
                float4 kw = *(const float4*)&kdw[(ky * 3 + kx) * C + c4];
                float4 vw = *(const float4*)&vdw[(ky * 3 + kx) * C + c4];
                ks[0] += xv.x * kw.x; ks[1] += xv.y * kw.y;
                ks[2] += xv.z * kw.z; ks[3] += xv.w * kw.w;
                vs[0] += xv.x * vw.x; vs[1] += xv.y * vw.y;
                vs[2] += xv.z * vw.z; vs[3] += xv.w * vw.w;
            }
        }
    }
    float4 ksc = *(const float4*)&kscale[c4];
    float4 kvr = *(const float4*)&kvar[c4];
    float4 kbi = *(const float4*)&kbias[c4];
    float4 kmn = *(const float4*)&kmean[c4];
    float4 vsc = *(const float4*)&vscale[c4];
    float4 vvr = *(const float4*)&vvar[c4];
    float4 vbi = *(const float4*)&vbias[c4];
    float4 vmn = *(const float4*)&vmean[c4];
    float kA[4] = {ksc.x * rsqrtf(kvr.x + EPS_BN), ksc.y * rsqrtf(kvr.y + EPS_BN),
                   ksc.z * rsqrtf(kvr.z + EPS_BN), ksc.w * rsqrtf(kvr.w + EPS_BN)};
    float kB[4] = {kbi.x - kmn.x * kA[0], kbi.y - kmn.y * kA[1],
                   kbi.z - kmn.z * kA[2], kbi.w - kmn.w * kA[3]};
    float vA[4] = {vsc.x * rsqrtf(vvr.x + EPS_BN), vsc.y * rsqrtf(vvr.y + EPS_BN),
                   vsc.z * rsqrtf(vvr.z + EPS_BN), vsc.w * rsqrtf(vvr.w + EPS_BN)};
    float vB[4] = {vbi.x - vmn.x * vA[0], vbi.y - vmn.y * vA[1],
                   vbi.z - vmn.z * vA[2], vbi.w - vmn.w * vA[3]};

    bf16x4 kh, kl, vh, vl;
#pragma unroll
    for (int j = 0; j < 4; j++) {
        float kf = ks[j] * kA[j] + kB[j];
        float vf = vs[j] * vA[j] + vB[j];
        bf16 h1 = (bf16)kf; kh[j] = h1; kl[j] = (bf16)(kf - (float)h1);
        bf16 h2 = (bf16)vf; vh[j] = h2; vl[j] = (bf16)(vf - (float)h2);
    }
    *(bf16x4*)&khi[(size_t)p * C + c4] = kh;
    *(bf16x4*)&klo[(size_t)p * C + c4] = kl;
    *(bf16x4*)&vhi[(size_t)p * C + c4] = vh;
    *(bf16x4*)&vlo[(size_t)p * C + c4] = vl;
}

// ---------------------------------------------------------------------------
// Kernel 2: MFMA GEMM out[M,192] = A(hi+lo)[M,192] x W[192,192].
// W staged fully in LDS once (one barrier); A frags read from global (L2-hot).
// EPI 0: q -> bf16 [M,192] * 0.125 ; EPI 1: k -> bf16 [M,192]
// EPI 2: v -> bf16 transposed [b*3+h][64 d][784 loc]
// ---------------------------------------------------------------------------
template <int EPI>
__global__ __launch_bounds__(256) void gemm2_kernel(const bf16* __restrict__ Ahi,
                                                    const bf16* __restrict__ Alo,
                                                    const bf16* __restrict__ Wt,
                                                    bf16* __restrict__ outp,
                                                    int Mtiles) {
    __shared__ bf16 Ws[192][200];   // [n][k], row pad 8 -> bank-uniform
    int t = threadIdx.x;
#pragma unroll
    for (int it = 0; it < 18; it++) {
        int idx = it * 256 + t;      // 0..4607 16B-chunks of 192x192
        int n = idx / 24, ck = idx - n * 24;
        *(uint4*)&Ws[n][ck * 8] = *(const uint4*)&Wt[n * 192 + ck * 8];
    }
    __syncthreads();

    int lane = t & 63, wid = t >> 6;
    int l16 = lane & 15, quad = lane >> 4;
    int wrow = wid * 16;

    for (int mt = blockIdx.x; mt < Mtiles; mt += gridDim.x) {
        int m0 = mt * 64;
        f32x4 acc[12];
#pragma unroll
        for (int n = 0; n < 12; n++) acc[n] = f32x4{0.f, 0.f, 0.f, 0.f};

        const bf16* arh = Ahi + (size_t)(m0 + wrow + l16) * 192;
        const bf16* arl = Alo + (size_t)(m0 + wrow + l16) * 192;
#pragma unroll
        for (int kc = 0; kc < 6; kc++) {
            bf16x8 ah = *(const bf16x8*)(arh + kc * 32 + quad * 8);
            bf16x8 al = *(const bf16x8*)(arl + kc * 32 + quad * 8);
#pragma unroll
            for (int n = 0; n < 12; n++) {
                bf16x8 bfr = *(const bf16x8*)&Ws[n * 16 + l16][kc * 32 + quad * 8];
                acc[n] = __builtin_amdgcn_mfma_f32_16x16x32_bf16(al, bfr, acc[n], 0, 0, 0);
                acc[n] = __builtin_amdgcn_mfma_f32_16x16x32_bf16(ah, bfr, acc[n], 0, 0, 0);
            }
        }

        if (EPI == 2) {
#pragma unroll
            for (int reg = 0; reg < 4; reg++) {
                int row = m0 + wrow + quad * 4 + reg;
                int b = row / 784;
                int loc = row - b * 784;
#pragma unroll
                for (int n = 0; n < 12; n++) {
                    int col = n * 16 + l16;
                    int h = col >> 6, d = col & 63;
                    outp[(((size_t)b * 3 + h) * 64 + d) * 784 + loc] = (bf16)acc[n][reg];
                }
            }
        } else {
            const float s = (EPI == 0) ? 0.125f : 1.0f;
#pragma unroll
            for (int reg = 0; reg < 4; reg++) {
                size_t row = m0 + wrow + quad * 4 + reg;
#pragma unroll
                for (int n = 0; n < 12; n++)
                    outp[row * 192 + n * 16 + l16] = (bf16)(acc[n][reg] * s);
            }
        }
    }
}

// ---------------------------------------------------------------------------
// Kernel 3: flash attention with bf16 MFMA (unchanged, verified).
// ---------------------------------------------------------------------------
__global__ __launch_bounds__(256) void attn_mfma_kernel(const bf16* __restrict__ qb,
                                                        const bf16* __restrict__ kb,
                                                        const bf16* __restrict__ vtb,
                                                        float* __restrict__ out) {
    const int LQ = 3136, LK = 784, C = 192, H = 3;
    int qt = blockIdx.x, h = blockIdx.y, b = blockIdx.z;

    __shared__ bf16 Qs[64][72];
    __shared__ bf16 Ks[64][72];
    __shared__ bf16 Vts[64][72];
    __shared__ bf16 Ps[64][72];

    int t    = threadIdx.x;
    int lane = t & 63;
    int wid  = t >> 6;
    int l16  = lane & 15;
    int quad = lane >> 4;
    int wrow = wid * 16;

    {
        const bf16* qbase = qb + ((size_t)b * LQ + qt * 64) * C + h * 64;
#pragma unroll
        for (int it = 0; it < 2; it++) {
            int e = t + it * 256;
            int r = e >> 3, s = e & 7;
            uint4 val = *(const uint4*)(qbase + (size_t)r * C + s * 8);
            *(uint4*)&Qs[r][s * 8] = val;
        }
    }

    float m_run[4], l_run[4];
    f32x4 o_acc[4];
#pragma unroll
    for (int i = 0; i < 4; i++) {
        m_run[i] = -INFINITY;
        l_run[i] = 0.f;
        o_acc[i] = f32x4{0.f, 0.f, 0.f, 0.f};
    }

    const bf16* kbase  = kb + (size_t)b * LK * C + h * 64;
    const bf16* vtbase = vtb + ((size_t)(b * H + h)) * 64 * LK;

    for (int j0 = 0; j0 < LK; j0 += 64) {
        __syncthreads();
#pragma unroll
        for (int it = 0; it < 2; it++) {
            int e = t + it * 256;
            int r = e >> 3, s = e & 7;
            int jg = j0 + r;
            uint4 val = make_uint4(0u, 0u, 0u, 0u);
            if (jg < LK) val = *(const uint4*)(kbase + (size_t)jg * C + s * 8);
            *(uint4*)&Ks[r][s * 8] = val;
        }
#pragma unroll
        for (int it = 0; it < 2; it++) {
            int e = t + it * 256;
            int r = e >> 3, s = e & 7;
            uint4 val = make_uint4(0u, 0u, 0u, 0u);
            if (j0 + s * 8 < LK) val = *(const uint4*)(vtbase + (size_t)r * LK + j0 + s * 8);
            *(uint4*)&Vts[r][s * 8] = val;
        }
        __syncthreads();

        f32x4 s_acc[4];
#pragma unroll
        for (int n = 0; n < 4; n++) s_acc[n] = f32x4{0.f, 0.f, 0.f, 0.f};
#pragma unroll
        for (int kk = 0; kk < 2; kk++) {
            bf16x8 afrag = *(const bf16x8*)&Qs[wrow + l16][kk * 32 + quad * 8];
#pragma unroll
            for (int n = 0; n < 4; n++) {
                bf16x8 bfrag = *(const bf16x8*)&Ks[n * 16 + l16][kk * 32 + quad * 8];
                s_acc[n] = __builtin_amdgcn_mfma_f32_16x16x32_bf16(afrag, bfrag, s_acc[n], 0, 0, 0);
            }
        }

        float rowmax[4];
#pragma unroll
        for (int reg = 0; reg < 4; reg++) {
            float mx = -INFINITY;
#pragma unroll
            for (int n = 0; n < 4; n++) {
                float sv = s_acc[n][reg];
                int j = j0 + n * 16 + l16;
                sv = (j < LK) ? sv : -INFINITY;
                s_acc[n][reg] = sv;
                mx = fmaxf(mx, sv);
            }
            rowmax[reg] = mx;
        }
#pragma unroll
        for (int m = 1; m < 16; m <<= 1)
#pragma unroll
            for (int reg = 0; reg < 4; reg++)
                rowmax[reg] = fmaxf(rowmax[reg], __shfl_xor(rowmax[reg], m, 64));

        float m_new[4], alpha[4], rowsum[4];
#pragma unroll
        for (int reg = 0; reg < 4; reg++) {
            m_new[reg] = fmaxf(m_run[reg], rowmax[reg]);
            alpha[reg] = __expf(m_run[reg] - m_new[reg]);
            float rs = 0.f;
#pragma unroll
            for (int n = 0; n < 4; n++) {
                float p = __expf(s_acc[n][reg] - m_new[reg]);
                rs += p;
                Ps[wrow + quad * 4 + reg][n * 16 + l16] = (bf16)p;
            }
            rowsum[reg] = rs;
        }
#pragma unroll
        for (int m = 1; m < 16; m <<= 1)
#pragma unroll
            for (int reg = 0; reg < 4; reg++)
                rowsum[reg] += __shfl_xor(rowsum[reg], m, 64);
#pragma unroll
        for (int reg = 0; reg < 4; reg++) {
            l_run[reg] = l_run[reg] * alpha[reg] + rowsum[reg];
            m_run[reg] = m_new[reg];
        }
#pragma unroll
        for (int n = 0; n < 4; n++)
#pragma unroll
            for (int reg = 0; reg < 4; reg++)
                o_acc[n][reg] *= alpha[reg];

#pragma unroll
        for (int kk = 0; kk < 2; kk++) {
            bf16x8 pfrag = *(const bf16x8*)&Ps[wrow + l16][kk * 32 + quad * 8];
#pragma unroll
            for (int n = 0; n < 4; n++) {
                bf16x8 vfrag = *(const bf16x8*)&Vts[n * 16 + l16][kk * 32 + quad * 8];
                o_acc[n] = __builtin_amdgcn_mfma_f32_16x16x32_bf16(pfrag, vfrag, o_acc[n], 0, 0, 0);
            }
        }
    }

    float* obase = out + ((size_t)b * LQ + qt * 64 + wrow) * C + h * 64;
#pragma unroll
    for (int reg = 0; reg < 4; reg++) {
        float invl = 1.f / l_run[reg];
#pragma unroll
        for (int n = 0; n < 4; n++)
            obase[(size_t)(quad * 4 + reg) * C + n * 16 + l16] = o_acc[n][reg] * invl;
    }
}

// ---------------------------------------------------------------------------
extern "C" void kernel_launch(void* const* d_in, const int* in_sizes, int n_in,
                              void* d_out, int out_size, void* d_ws, size_t ws_size,
                              hipStream_t stream) {
    const float* x = (const float*)d_in[0];

    const float* q_dw = (const float*)d_in[1];
    const float* q_scale = (const float*)d_in[2];
    const float* q_bias = (const float*)d_in[3];
    const float* q_mean = (const float*)d_in[4];
    const float* q_var = (const float*)d_in[5];
    const float* q_pw = (const float*)d_in[6];

    const float* k_dw = (const float*)d_in[7];
    const float* k_scale = (const float*)d_in[8];
    const float* k_bias = (const float*)d_in[9];
    const float* k_mean = (const float*)d_in[10];
    const float* k_var = (const float*)d_in[11];
    const float* k_pw = (const float*)d_in[12];

    const float* v_dw = (const float*)d_in[13];
    const float* v_scale = (const float*)d_in[14];
    const float* v_bias = (const float*)d_in[15];
    const float* v_mean = (const float*)d_in[16];
    const float* v_var = (const float*)d_in[17];
    const float* v_pw = (const float*)d_in[18];

    float* out = (float*)d_out;

    // workspace layout (bytes, all 16B aligned)
    char* ws = (char*)d_ws;
    bf16* qhi = (bf16*)(ws);                  // 9,633,792
    bf16* qlo = (bf16*)(ws + 9633792);        // 9,633,792
    bf16* khi = (bf16*)(ws + 19267584);       // 2,408,448
    bf16* klo = (bf16*)(ws + 21676032);       // 2,408,448
    bf16* vhi = (bf16*)(ws + 24084480);       // 2,408,448
    bf16* vlo = (bf16*)(ws + 26492928);       // 2,408,448
    bf16* qbuf = (bf16*)(ws + 28901376);      // 9,633,792
    bf16* kbuf = (bf16*)(ws + 38535168);      // 2,408,448
    bf16* vtbuf = (bf16*)(ws + 40943616);     // 2,408,448
    bf16* wt = (bf16*)(ws + 43352064);        // 221,184

    cast_w_kernel<<<432, 256, 0, stream>>>(q_pw, k_pw, v_pw, wt);

    // stage 1: convs (25088*48/256 = 4704 blocks; 6272*48/256 = 1176 blocks)
    conv_q_kernel<<<4704, 256, 0, stream>>>(x, q_dw, q_scale, q_bias, q_mean, q_var,
                                            qhi, qlo);
    conv_kv_kernel<<<1176, 256, 0, stream>>>(x, k_dw, k_scale, k_bias, k_mean, k_var,
                                             v_dw, v_scale, v_bias, v_mean, v_var,
                                             khi, klo, vhi, vlo);

    // stage 2: MFMA GEMMs (Mtiles: 392 for Q, 98 for K/V)
    gemm2_kernel<0><<<392, 256, 0, stream>>>(qhi, qlo, wt, qbuf, 392);
    gemm2_kernel<1><<<98, 256, 0, stream>>>(khi, klo, wt + 36864, kbuf, 98);
    gemm2_kernel<2><<<98, 256, 0, stream>>>(vhi, vlo, wt + 2 * 36864, vtbuf, 98);

    // attention: grid (49 q-tiles, 3 heads, 8 batches)
    attn_mfma_kernel<<<dim3(3136 / 64, 3, 8), 256, 0, stream>>>(qbuf, kbuf, vtbuf, out);
}

// Round 5
// 229.231 us; speedup vs baseline: 2.6872x; 1.0182x over previous
//
#include <hip/hip_runtime.h>
#include <cmath>

#define EPS_BN 1e-5f

typedef __bf16 bf16;
typedef __bf16 bf16x4 __attribute__((ext_vector_type(4)));
typedef __bf16 bf16x8 __attribute__((ext_vector_type(8)));
typedef float  f32x4  __attribute__((ext_vector_type(4)));

// ---------------------------------------------------------------------------
// Kernel 1: all preprocessing elementwise work in one launch.
//   blocks [0, 4704)        : Q dwconv s1/p1 + BN -> hi/lo bf16
//   blocks [4704, 5880)     : K+V dwconv s2/p0 + BN -> hi/lo bf16 (shared x)
//   blocks [5880, 6312)     : cast+transpose 3 pointwise weights -> bf16 Wt[n][k]
// ---------------------------------------------------------------------------
__global__ __launch_bounds__(256) void conv_all_kernel(
    const float* __restrict__ x,
    const float* __restrict__ qdw, const float* __restrict__ qscale,
    const float* __restrict__ qbias, const float* __restrict__ qmean,
    const float* __restrict__ qvar,
    const float* __restrict__ kdw, const float* __restrict__ kscale,
    const float* __restrict__ kbias, const float* __restrict__ kmean,
    const float* __restrict__ kvar,
    const float* __restrict__ vdw, const float* __restrict__ vscale,
    const float* __restrict__ vbias, const float* __restrict__ vmean,
    const float* __restrict__ vvar,
    const float* __restrict__ qpw, const float* __restrict__ kpw,
    const float* __restrict__ vpw,
    bf16* __restrict__ qhi, bf16* __restrict__ qlo,
    bf16* __restrict__ khi, bf16* __restrict__ klo,
    bf16* __restrict__ vhi, bf16* __restrict__ vlo,
    bf16* __restrict__ wt) {
    const int WW = 56, C = 192;
    int bid = blockIdx.x;

    if (bid < 4704) {
        // ---- Q conv: stride 1, pad 1 ----
        int idx = bid * 256 + threadIdx.x;
        int p  = idx / 48;
        int c4 = (idx - p * 48) * 4;
        int b  = p / 3136;
        int rem = p - b * 3136;
        int oy = rem / 56;
        int ox = rem - oy * 56;
        const float* xb = x + (size_t)b * 3136 * C;

        float4 sc = *(const float4*)&qscale[c4];
        float4 vr = *(const float4*)&qvar[c4];
        float4 bi = *(const float4*)&qbias[c4];
        float4 mn = *(const float4*)&qmean[c4];
        float aA[4] = {sc.x * rsqrtf(vr.x + EPS_BN), sc.y * rsqrtf(vr.y + EPS_BN),
                       sc.z * rsqrtf(vr.z + EPS_BN), sc.w * rsqrtf(vr.w + EPS_BN)};
        float aB[4] = {bi.x - mn.x * aA[0], bi.y - mn.y * aA[1],
                       bi.z - mn.z * aA[2], bi.w - mn.w * aA[3]};
        float s[4] = {0.f, 0.f, 0.f, 0.f};
#pragma unroll
        for (int ky = 0; ky < 3; ky++) {
            int iy = oy + ky - 1;
            bool yok = (iy >= 0) && (iy < 56);
#pragma unroll
            for (int kx = 0; kx < 3; kx++) {
                int ix = ox + kx - 1;
                if (yok && ix >= 0 && ix < WW) {
                    float4 xv = *(const float4*)&xb[((size_t)iy * WW + ix) * C + c4];
                    float4 wv = *(const float4*)&qdw[(ky * 3 + kx) * C + c4];
                    s[0] += xv.x * wv.x; s[1] += xv.y * wv.y;
                    s[2] += xv.z * wv.z; s[3] += xv.w * wv.w;
                }
            }
        }
        bf16x4 hv, lv;
#pragma unroll
        for (int j = 0; j < 4; j++) {
            float av = s[j] * aA[j] + aB[j];
            bf16 hh = (bf16)av;
            hv[j] = hh;
            lv[j] = (bf16)(av - (float)hh);
        }
        *(bf16x4*)&qhi[(size_t)p * C + c4] = hv;
        *(bf16x4*)&qlo[(size_t)p * C + c4] = lv;
    } else if (bid < 5880) {
        // ---- K+V conv: stride 2, pad 0 ----
        int idx = (bid - 4704) * 256 + threadIdx.x;
        int p  = idx / 48;
        int c4 = (idx - p * 48) * 4;
        int b  = p / 784;
        int rem = p - b * 784;
        int oy = rem / 28;
        int ox = rem - oy * 28;
        const float* xb = x + (size_t)b * 3136 * C;

        float ks[4] = {0.f, 0.f, 0.f, 0.f};
        float vs[4] = {0.f, 0.f, 0.f, 0.f};
#pragma unroll
        for (int ky = 0; ky < 3; ky++) {
            int iy = oy * 2 + ky;
            bool yok = iy < 56;
#pragma unroll
            for (int kx = 0; kx < 3; kx++) {
                int ix = ox * 2 + kx;
                if (yok && ix < WW) {
                    float4 xv = *(const float4*)&xb[((size_t)iy * WW + ix) * C + c4];
                    float4 kw = *(const float4*)&kdw[(ky * 3 + kx) * C + c4];
                    float4 vw = *(const float4*)&vdw[(ky * 3 + kx) * C + c4];
                    ks[0] += xv.x * kw.x; ks[1] += xv.y * kw.y;
                    ks[2] += xv.z * kw.z; ks[3] += xv.w * kw.w;
                    vs[0] += xv.x * vw.x; vs[1] += xv.y * vw.y;
                    vs[2] += xv.z * vw.z; vs[3] += xv.w * vw.w;
                }
            }
        }
        float4 ksc = *(const float4*)&kscale[c4];
        float4 kvr = *(const float4*)&kvar[c4];
        float4 kbi = *(const float4*)&kbias[c4];
        float4 kmn = *(const float4*)&kmean[c4];
        float4 vsc = *(const float4*)&vscale[c4];
        float4 vvr = *(const float4*)&vvar[c4];
        float4 vbi = *(const float4*)&vbias[c4];
        float4 vmn = *(const float4*)&vmean[c4];
        float kA[4] = {ksc.x * rsqrtf(kvr.x + EPS_BN), ksc.y * rsqrtf(kvr.y + EPS_BN),
                       ksc.z * rsqrtf(kvr.z + EPS_BN), ksc.w * rsqrtf(kvr.w + EPS_BN)};
        float kB[4] = {kbi.x - kmn.x * kA[0], kbi.y - kmn.y * kA[1],
                       kbi.z - kmn.z * kA[2], kbi.w - kmn.w * kA[3]};
        float vA[4] = {vsc.x * rsqrtf(vvr.x + EPS_BN), vsc.y * rsqrtf(vvr.y + EPS_BN),
                       vsc.z * rsqrtf(vvr.z + EPS_BN), vsc.w * rsqrtf(vvr.w + EPS_BN)};
        float vB[4] = {vbi.x - vmn.x * vA[0], vbi.y - vmn.y * vA[1],
                       vbi.z - vmn.z * vA[2], vbi.w - vmn.w * vA[3]};
        bf16x4 kh, kl, vh, vl;
#pragma unroll
        for (int j = 0; j < 4; j++) {
            float kf = ks[j] * kA[j] + kB[j];
            float vf = vs[j] * vA[j] + vB[j];
            bf16 h1 = (bf16)kf; kh[j] = h1; kl[j] = (bf16)(kf - (float)h1);
            bf16 h2 = (bf16)vf; vh[j] = h2; vl[j] = (bf16)(vf - (float)h2);
        }
        *(bf16x4*)&khi[(size_t)p * C + c4] = kh;
        *(bf16x4*)&klo[(size_t)p * C + c4] = kl;
        *(bf16x4*)&vhi[(size_t)p * C + c4] = vh;
        *(bf16x4*)&vlo[(size_t)p * C + c4] = vl;
    } else {
        // ---- weight cast + transpose ----
        int idx = (bid - 5880) * 256 + threadIdx.x;
        if (idx < 3 * 36864) {
            int mat = idx / 36864, r = idx % 36864;
            int n = r / 192, k = r - n * 192;
            const float* src = (mat == 0) ? qpw : (mat == 1) ? kpw : vpw;
            wt[idx] = (bf16)src[k * 192 + n];
        }
    }
}

// ---------------------------------------------------------------------------
// Kernel 2: all three pointwise GEMMs in one launch.
// out[64,192] = A(hi+lo)[64,192] x W[192,192] per block, W staged in LDS once.
//   blocks [0,392): Q (epi: bf16 *0.125), [392,490): K (bf16), [490,588): V
//   (bf16 transposed [b*3+h][64 d][784 loc]).
// ---------------------------------------------------------------------------
__global__ __launch_bounds__(256) void gemm_all_kernel(
    const bf16* __restrict__ qhi, const bf16* __restrict__ qlo,
    const bf16* __restrict__ khi, const bf16* __restrict__ klo,
    const bf16* __restrict__ vhi, const bf16* __restrict__ vlo,
    const bf16* __restrict__ wt,
    bf16* __restrict__ qbuf, bf16* __restrict__ kbuf, bf16* __restrict__ vtbuf) {
    __shared__ bf16 Ws[192][200];
    int t = threadIdx.x;
    int bid = blockIdx.x;

    int mode, mt;
    const bf16 *Ahi, *Alo, *Wsrc;
    if (bid < 392)      { mode = 0; mt = bid;       Ahi = qhi; Alo = qlo; Wsrc = wt; }
    else if (bid < 490) { mode = 1; mt = bid - 392; Ahi = khi; Alo = klo; Wsrc = wt + 36864; }
    else                { mode = 2; mt = bid - 490; Ahi = vhi; Alo = vlo; Wsrc = wt + 73728; }

#pragma unroll
    for (int it = 0; it < 18; it++) {
        int idx = it * 256 + t;
        int n = idx / 24, ck = idx - n * 24;
        *(uint4*)&Ws[n][ck * 8] = *(const uint4*)&Wsrc[n * 192 + ck * 8];
    }
    __syncthreads();

    int lane = t & 63, wid = t >> 6;
    int l16 = lane & 15, quad = lane >> 4;
    int wrow = wid * 16;
    int m0 = mt * 64;

    f32x4 acc[12];
#pragma unroll
    for (int n = 0; n < 12; n++) acc[n] = f32x4{0.f, 0.f, 0.f, 0.f};

    const bf16* arh = Ahi + (size_t)(m0 + wrow + l16) * 192;
    const bf16* arl = Alo + (size_t)(m0 + wrow + l16) * 192;
#pragma unroll
    for (int kc = 0; kc < 6; kc++) {
        bf16x8 ah = *(const bf16x8*)(arh + kc * 32 + quad * 8);
        bf16x8 al = *(const bf16x8*)(arl + kc * 32 + quad * 8);
#pragma unroll
        for (int n = 0; n < 12; n++) {
            bf16x8 bfr = *(const bf16x8*)&Ws[n * 16 + l16][kc * 32 + quad * 8];
            acc[n] = __builtin_amdgcn_mfma_f32_16x16x32_bf16(al, bfr, acc[n], 0, 0, 0);
            acc[n] = __builtin_amdgcn_mfma_f32_16x16x32_bf16(ah, bfr, acc[n], 0, 0, 0);
        }
    }

    if (mode == 2) {
#pragma unroll
        for (int reg = 0; reg < 4; reg++) {
            int row = m0 + wrow + quad * 4 + reg;
            int b = row / 784;
            int loc = row - b * 784;
#pragma unroll
            for (int n = 0; n < 12; n++) {
                int col = n * 16 + l16;
                int h = col >> 6, d = col & 63;
                vtbuf[(((size_t)b * 3 + h) * 64 + d) * 784 + loc] = (bf16)acc[n][reg];
            }
        }
    } else {
        bf16* outp = (mode == 0) ? qbuf : kbuf;
        const float s = (mode == 0) ? 0.125f : 1.0f;
#pragma unroll
        for (int reg = 0; reg < 4; reg++) {
            size_t row = m0 + wrow + quad * 4 + reg;
#pragma unroll
            for (int n = 0; n < 12; n++)
                outp[row * 192 + n * 16 + l16] = (bf16)(acc[n][reg] * s);
        }
    }
}

// ---------------------------------------------------------------------------
// Kernel 3: flash attention, S^T formulation. BK=112 (784=7x112, no masking).
// Block = 64 q x (head, batch), 4 waves x 16 q. Q frags in registers.
// S^T = mfma(A=K, B=Q): lane holds col q=l16, rows key=quad*4+reg ->
// per-lane scalar softmax state, 2-step cross-quad shuffle reductions,
// P written as b64, read as b128. O^T = mfma(A=Vt, B=P): col q=l16 again.
// Register prefetch of next K/V chunk overlaps MFMA+softmax.
// ---------------------------------------------------------------------------
__global__ __launch_bounds__(256) void attn2_kernel(const bf16* __restrict__ qb,
                                                    const bf16* __restrict__ kb,
                                                    const bf16* __restrict__ vtb,
                                                    float* __restrict__ out) {
    const int LQ = 3136, LK = 784, C = 192;
    int qt = blockIdx.x, h = blockIdx.y, b = blockIdx.z;

    __shared__ bf16 Ks[112][72];    // [key][d]
    __shared__ bf16 Vts[64][136];   // [d][key], cols 112..127 zeroed
    __shared__ bf16 Ps[64][136];    // [q][key],  cols 112..127 zeroed

    int t    = threadIdx.x;
    int lane = t & 63;
    int wid  = t >> 6;
    int l16  = lane & 15;
    int quad = lane >> 4;
    int wrow = wid * 16;

    // zero the key-pad regions once (cols 112..127)
    if (t < 128) {
        int row = t >> 1, part = t & 1;
        *(uint4*)&Ps[row][112 + part * 8] = make_uint4(0u, 0u, 0u, 0u);
    } else {
        int tt = t - 128;
        int row = tt >> 1, part = tt & 1;
        *(uint4*)&Vts[row][112 + part * 8] = make_uint4(0u, 0u, 0u, 0u);
    }

    // Q fragments (B operand: n = q = l16, k = d) held in registers
    bf16x8 qfrag[2];
    {
        const bf16* qrow = qb + ((size_t)b * LQ + qt * 64 + wrow + l16) * C + h * 64;
        qfrag[0] = *(const bf16x8*)(qrow + quad * 8);
        qfrag[1] = *(const bf16x8*)(qrow + 32 + quad * 8);
    }

    const bf16* kbase  = kb + (size_t)b * LK * C + h * 64;
    const bf16* vtbase = vtb + ((size_t)(b * 3 + h)) * 64 * LK;

    // prefetch chunk 0 into registers (1792 uint4 tasks = 7 per thread)
    uint4 pf[7];
#pragma unroll
    for (int i = 0; i < 7; i++) {
        int task = i * 256 + t;
        if (task < 896) {
            int row = task >> 3, s = task & 7;
            pf[i] = *(const uint4*)(kbase + (size_t)row * C + s * 8);
        } else {
            int i2 = task - 896;
            int ck = i2 % 14, d = i2 / 14;
            pf[i] = *(const uint4*)(vtbase + (size_t)d * LK + ck * 8);
        }
    }

    float m_run = -INFINITY, l_run = 0.f;
    f32x4 o_acc[4];
#pragma unroll
    for (int dt = 0; dt < 4; dt++) o_acc[dt] = f32x4{0.f, 0.f, 0.f, 0.f};

    for (int c = 0; c < 7; c++) {
        __syncthreads();   // prior chunk's readers done
        // registers -> LDS
#pragma unroll
        for (int i = 0; i < 7; i++) {
            int task = i * 256 + t;
            if (task < 896) {
                int row = task >> 3, s = task & 7;
                *(uint4*)&Ks[row][s * 8] = pf[i];
            } else {
                int i2 = task - 896;
                int ck = i2 % 14, d = i2 / 14;
                *(uint4*)&Vts[d][ck * 8] = pf[i];
            }
        }
        __syncthreads();
        // issue next chunk's loads (in flight during compute)
        if (c < 6) {
            int j0n = (c + 1) * 112;
#pragma unroll
            for (int i = 0; i < 7; i++) {
                int task = i * 256 + t;
                if (task < 896) {
                    int row = task >> 3, s = task & 7;
                    pf[i] = *(const uint4*)(kbase + (size_t)(j0n + row) * C + s * 8);
                } else {
                    int i2 = task - 896;
                    int ck = i2 % 14, d = i2 / 14;
                    pf[i] = *(const uint4*)(vtbase + (size_t)d * LK + j0n + ck * 8);
                }
            }
        }

        // S^T = K Q^T : 7 key-tiles x (K-dim 64 = 2 steps)
        f32x4 st[7];
#pragma unroll
        for (int kb7 = 0; kb7 < 7; kb7++) st[kb7] = f32x4{0.f, 0.f, 0.f, 0.f};
#pragma unroll
        for (int kk = 0; kk < 2; kk++) {
#pragma unroll
            for (int kb7 = 0; kb7 < 7; kb7++) {
                bf16x8 afrag = *(const bf16x8*)&Ks[kb7 * 16 + l16][kk * 32 + quad * 8];
                st[kb7] = __builtin_amdgcn_mfma_f32_16x16x32_bf16(afrag, qfrag[kk], st[kb7], 0, 0, 0);
            }
        }

        // online softmax for q = l16 (28 keys in-lane, cross-quad shuffles)
        float mx = -INFINITY;
#pragma unroll
        for (int kb7 = 0; kb7 < 7; kb7++)
#pragma unroll
            for (int r = 0; r < 4; r++) mx = fmaxf(mx, st[kb7][r]);
        mx = fmaxf(mx, __shfl_xor(mx, 16, 64));
        mx = fmaxf(mx, __shfl_xor(mx, 32, 64));
        float m_new = fmaxf(m_run, mx);
        float alpha = __expf(m_run - m_new);   // chunk 0: exp(-inf)=0

        float rs = 0.f;
#pragma unroll
        for (int kb7 = 0; kb7 < 7; kb7++) {
            bf16x4 pv;
#pragma unroll
            for (int r = 0; r < 4; r++) {
                float p = __expf(st[kb7][r] - m_new);
                rs += p;
                pv[r] = (bf16)p;
            }
            *(bf16x4*)&Ps[wrow + l16][kb7 * 16 + quad * 4] = pv;
        }
        rs += __shfl_xor(rs, 16, 64);
        rs += __shfl_xor(rs, 32, 64);
        l_run = l_run * alpha + rs;
        m_run = m_new;
#pragma unroll
        for (int dt = 0; dt < 4; dt++)
#pragma unroll
            for (int r = 0; r < 4; r++) o_acc[dt][r] *= alpha;

        // O^T += Vt P^T : keys 128 (16 zero-padded) = 4 steps
#pragma unroll
        for (int kk = 0; kk < 4; kk++) {
            bf16x8 pfrag = *(const bf16x8*)&Ps[wrow + l16][kk * 32 + quad * 8];
#pragma unroll
            for (int dt = 0; dt < 4; dt++) {
                bf16x8 vfrag = *(const bf16x8*)&Vts[dt * 16 + l16][kk * 32 + quad * 8];
                o_acc[dt] = __builtin_amdgcn_mfma_f32_16x16x32_bf16(vfrag, pfrag, o_acc[dt], 0, 0, 0);
            }
        }
    }

    // epilogue: lane holds q = l16, d = dt*16 + quad*4 + reg -> float4 stores
    float invl = 1.f / l_run;
    float* ob = out + ((size_t)b * LQ + qt * 64 + wrow + l16) * C + h * 64;
#pragma unroll
    for (int dt = 0; dt < 4; dt++) {
        float4 v4 = {o_acc[dt][0] * invl, o_acc[dt][1] * invl,
                     o_acc[dt][2] * invl, o_acc[dt][3] * invl};
        *(float4*)(ob + dt * 16 + quad * 4) = v4;
    }
}

// ---------------------------------------------------------------------------
extern "C" void kernel_launch(void* const* d_in, const int* in_sizes, int n_in,
                              void* d_out, int out_size, void* d_ws, size_t ws_size,
                              hipStream_t stream) {
    const float* x = (const float*)d_in[0];

    const float* q_dw = (const float*)d_in[1];
    const float* q_scale = (const float*)d_in[2];
    const float* q_bias = (const float*)d_in[3];
    const float* q_mean = (const float*)d_in[4];
    const float* q_var = (const float*)d_in[5];
    const float* q_pw = (const float*)d_in[6];

    const float* k_dw = (const float*)d_in[7];
    const float* k_scale = (const float*)d_in[8];
    const float* k_bias = (const float*)d_in[9];
    const float* k_mean = (const float*)d_in[10];
    const float* k_var = (const float*)d_in[11];
    const float* k_pw = (const float*)d_in[12];

    const float* v_dw = (const float*)d_in[13];
    const float* v_scale = (const float*)d_in[14];
    const float* v_bias = (const float*)d_in[15];
    const float* v_mean = (const float*)d_in[16];
    const float* v_var = (const float*)d_in[17];
    const float* v_pw = (const float*)d_in[18];

    float* out = (float*)d_out;

    // workspace layout (bytes, all 16B aligned)
    char* ws = (char*)d_ws;
    bf16* qhi = (bf16*)(ws);                  // 9,633,792
    bf16* qlo = (bf16*)(ws + 9633792);        // 9,633,792
    bf16* khi = (bf16*)(ws + 19267584);       // 2,408,448
    bf16* klo = (bf16*)(ws + 21676032);       // 2,408,448
    bf16* vhi = (bf16*)(ws + 24084480);       // 2,408,448
    bf16* vlo = (bf16*)(ws + 26492928);       // 2,408,448
    bf16* qbuf = (bf16*)(ws + 28901376);      // 9,633,792
    bf16* kbuf = (bf16*)(ws + 38535168);      // 2,408,448
    bf16* vtbuf = (bf16*)(ws + 40943616);     // 2,408,448
    bf16* wt = (bf16*)(ws + 43352064);        // 221,184

    // stage 1: conv(Q) + conv(K,V) + weight cast, one launch (6312 blocks)
    conv_all_kernel<<<6312, 256, 0, stream>>>(
        x,
        q_dw, q_scale, q_bias, q_mean, q_var,
        k_dw, k_scale, k_bias, k_mean, k_var,
        v_dw, v_scale, v_bias, v_mean, v_var,
        q_pw, k_pw, v_pw,
        qhi, qlo, khi, klo, vhi, vlo, wt);

    // stage 2: all three pointwise GEMMs, one launch (588 blocks)
    gemm_all_kernel<<<588, 256, 0, stream>>>(
        qhi, qlo, khi, klo, vhi, vlo, wt, qbuf, kbuf, vtbuf);

    // stage 3: attention (49 q-tiles, 3 heads, 8 batches)
    attn2_kernel<<<dim3(49, 3, 8), 256, 0, stream>>>(qbuf, kbuf, vtbuf, out);
}

// Round 6
// 227.108 us; speedup vs baseline: 2.7123x; 1.0093x over previous
//
#include <hip/hip_runtime.h>
#include <cmath>

#define EPS_BN 1e-5f

typedef __bf16 bf16;
typedef __bf16 bf16x4 __attribute__((ext_vector_type(4)));
typedef __bf16 bf16x8 __attribute__((ext_vector_type(8)));
typedef float  f32x4  __attribute__((ext_vector_type(4)));

// ---------------------------------------------------------------------------
// Kernel 1: all preprocessing elementwise work in one launch.
//   blocks [0, 4704)        : Q dwconv s1/p1 + BN -> hi/lo bf16
//   blocks [4704, 5880)     : K+V dwconv s2/p0 + BN -> hi/lo bf16 (shared x)
//   blocks [5880, 6312)     : cast+transpose 3 pointwise weights -> bf16 Wt[n][k]
// ---------------------------------------------------------------------------
__global__ __launch_bounds__(256) void conv_all_kernel(
    const float* __restrict__ x,
    const float* __restrict__ qdw, const float* __restrict__ qscale,
    const float* __restrict__ qbias, const float* __restrict__ qmean,
    const float* __restrict__ qvar,
    const float* __restrict__ kdw, const float* __restrict__ kscale,
    const float* __restrict__ kbias, const float* __restrict__ kmean,
    const float* __restrict__ kvar,
    const float* __restrict__ vdw, const float* __restrict__ vscale,
    const float* __restrict__ vbias, const float* __restrict__ vmean,
    const float* __restrict__ vvar,
    const float* __restrict__ qpw, const float* __restrict__ kpw,
    const float* __restrict__ vpw,
    bf16* __restrict__ qhi, bf16* __restrict__ qlo,
    bf16* __restrict__ khi, bf16* __restrict__ klo,
    bf16* __restrict__ vhi, bf16* __restrict__ vlo,
    bf16* __restrict__ wt) {
    const int WW = 56, C = 192;
    int bid = blockIdx.x;

    if (bid < 4704) {
        // ---- Q conv: stride 1, pad 1 ----
        int idx = bid * 256 + threadIdx.x;
        int p  = idx / 48;
        int c4 = (idx - p * 48) * 4;
        int b  = p / 3136;
        int rem = p - b * 3136;
        int oy = rem / 56;
        int ox = rem - oy * 56;
        const float* xb = x + (size_t)b * 3136 * C;

        float4 sc = *(const float4*)&qscale[c4];
        float4 vr = *(const float4*)&qvar[c4];
        float4 bi = *(const float4*)&qbias[c4];
        float4 mn = *(const float4*)&qmean[c4];
        float aA[4] = {sc.x * rsqrtf(vr.x + EPS_BN), sc.y * rsqrtf(vr.y + EPS_BN),
                       sc.z * rsqrtf(vr.z + EPS_BN), sc.w * rsqrtf(vr.w + EPS_BN)};
        float aB[4] = {bi.x - mn.x * aA[0], bi.y - mn.y * aA[1],
                       bi.z - mn.z * aA[2], bi.w - mn.w * aA[3]};
        float s[4] = {0.f, 0.f, 0.f, 0.f};
#pragma unroll
        for (int ky = 0; ky < 3; ky++) {
            int iy = oy + ky - 1;
            bool yok = (iy >= 0) && (iy < 56);
#pragma unroll
            for (int kx = 0; kx < 3; kx++) {
                int ix = ox + kx - 1;
                if (yok && ix >= 0 && ix < WW) {
                    float4 xv = *(const float4*)&xb[((size_t)iy * WW + ix) * C + c4];
                    float4 wv = *(const float4*)&qdw[(ky * 3 + kx) * C + c4];
                    s[0] += xv.x * wv.x; s[1] += xv.y * wv.y;
                    s[2] += xv.z * wv.z; s[3] += xv.w * wv.w;
                }
            }
        }
        bf16x4 hv, lv;
#pragma unroll
        for (int j = 0; j < 4; j++) {
            float av = s[j] * aA[j] + aB[j];
            bf16 hh = (bf16)av;
            hv[j] = hh;
            lv[j] = (bf16)(av - (float)hh);
        }
        *(bf16x4*)&qhi[(size_t)p * C + c4] = hv;
        *(bf16x4*)&qlo[(size_t)p * C + c4] = lv;
    } else if (bid < 5880) {
        // ---- K+V conv: stride 2, pad 0 ----
        int idx = (bid - 4704) * 256 + threadIdx.x;
        int p  = idx / 48;
        int c4 = (idx - p * 48) * 4;
        int b  = p / 784;
        int rem = p - b * 784;
        int oy = rem / 28;
        int ox = rem - oy * 28;
        const float* xb = x + (size_t)b * 3136 * C;

        float ks[4] = {0.f, 0.f, 0.f, 0.f};
        float vs[4] = {0.f, 0.f, 0.f, 0.f};
#pragma unroll
        for (int ky = 0; ky < 3; ky++) {
            int iy = oy * 2 + ky;
            bool yok = iy < 56;
#pragma unroll
            for (int kx = 0; kx < 3; kx++) {
                int ix = ox * 2 + kx;
                if (yok && ix < WW) {
                    float4 xv = *(const float4*)&xb[((size_t)iy * WW + ix) * C + c4];
                    float4 kw = *(const float4*)&kdw[(ky * 3 + kx) * C + c4];
                    float4 vw = *(const float4*)&vdw[(ky * 3 + kx) * C + c4];
                    ks[0] += xv.x * kw.x; ks[1] += xv.y * kw.y;
                    ks[2] += xv.z * kw.z; ks[3] += xv.w * kw.w;
                    vs[0] += xv.x * vw.x; vs[1] += xv.y * vw.y;
                    vs[2] += xv.z * vw.z; vs[3] += xv.w * vw.w;
                }
            }
        }
        float4 ksc = *(const float4*)&kscale[c4];
        float4 kvr = *(const float4*)&kvar[c4];
        float4 kbi = *(const float4*)&kbias[c4];
        float4 kmn = *(const float4*)&kmean[c4];
        float4 vsc = *(const float4*)&vscale[c4];
        float4 vvr = *(const float4*)&vvar[c4];
        float4 vbi = *(const float4*)&vbias[c4];
        float4 vmn = *(const float4*)&vmean[c4];
        float kA[4] = {ksc.x * rsqrtf(kvr.x + EPS_BN), ksc.y * rsqrtf(kvr.y + EPS_BN),
                       ksc.z * rsqrtf(kvr.z + EPS_BN), ksc.w * rsqrtf(kvr.w + EPS_BN)};
        float kB[4] = {kbi.x - kmn.x * kA[0], kbi.y - kmn.y * kA[1],
                       kbi.z - kmn.z * kA[2], kbi.w - kmn.w * kA[3]};
        float vA[4] = {vsc.x * rsqrtf(vvr.x + EPS_BN), vsc.y * rsqrtf(vvr.y + EPS_BN),
                       vsc.z * rsqrtf(vvr.z + EPS_BN), vsc.w * rsqrtf(vvr.w + EPS_BN)};
        float vB[4] = {vbi.x - vmn.x * vA[0], vbi.y - vmn.y * vA[1],
                       vbi.z - vmn.z * vA[2], vbi.w - vmn.w * vA[3]};
        bf16x4 kh, kl, vh, vl;
#pragma unroll
        for (int j = 0; j < 4; j++) {
            float kf = ks[j] * kA[j] + kB[j];
            float vf = vs[j] * vA[j] + vB[j];
            bf16 h1 = (bf16)kf; kh[j] = h1; kl[j] = (bf16)(kf - (float)h1);
            bf16 h2 = (bf16)vf; vh[j] = h2; vl[j] = (bf16)(vf - (float)h2);
        }
        *(bf16x4*)&khi[(size_t)p * C + c4] = kh;
        *(bf16x4*)&klo[(size_t)p * C + c4] = kl;
        *(bf16x4*)&vhi[(size_t)p * C + c4] = vh;
        *(bf16x4*)&vlo[(size_t)p * C + c4] = vl;
    } else {
        // ---- weight cast + transpose ----
        int idx = (bid - 5880) * 256 + threadIdx.x;
        if (idx < 3 * 36864) {
            int mat = idx / 36864, r = idx % 36864;
            int n = r / 192, k = r - n * 192;
            const float* src = (mat == 0) ? qpw : (mat == 1) ? kpw : vpw;
            wt[idx] = (bf16)src[k * 192 + n];
        }
    }
}

// ---------------------------------------------------------------------------
// Kernel 2: all three pointwise GEMMs in one launch.
// ---------------------------------------------------------------------------
__global__ __launch_bounds__(256) void gemm_all_kernel(
    const bf16* __restrict__ qhi, const bf16* __restrict__ qlo,
    const bf16* __restrict__ khi, const bf16* __restrict__ klo,
    const bf16* __restrict__ vhi, const bf16* __restrict__ vlo,
    const bf16* __restrict__ wt,
    bf16* __restrict__ qbuf, bf16* __restrict__ kbuf, bf16* __restrict__ vtbuf) {
    __shared__ bf16 Ws[192][200];
    int t = threadIdx.x;
    int bid = blockIdx.x;

    int mode, mt;
    const bf16 *Ahi, *Alo, *Wsrc;
    if (bid < 392)      { mode = 0; mt = bid;       Ahi = qhi; Alo = qlo; Wsrc = wt; }
    else if (bid < 490) { mode = 1; mt = bid - 392; Ahi = khi; Alo = klo; Wsrc = wt + 36864; }
    else                { mode = 2; mt = bid - 490; Ahi = vhi; Alo = vlo; Wsrc = wt + 73728; }

#pragma unroll
    for (int it = 0; it < 18; it++) {
        int idx = it * 256 + t;
        int n = idx / 24, ck = idx - n * 24;
        *(uint4*)&Ws[n][ck * 8] = *(const uint4*)&Wsrc[n * 192 + ck * 8];
    }
    __syncthreads();

    int lane = t & 63, wid = t >> 6;
    int l16 = lane & 15, quad = lane >> 4;
    int wrow = wid * 16;
    int m0 = mt * 64;

    f32x4 acc[12];
#pragma unroll
    for (int n = 0; n < 12; n++) acc[n] = f32x4{0.f, 0.f, 0.f, 0.f};

    const bf16* arh = Ahi + (size_t)(m0 + wrow + l16) * 192;
    const bf16* arl = Alo + (size_t)(m0 + wrow + l16) * 192;
#pragma unroll
    for (int kc = 0; kc < 6; kc++) {
        bf16x8 ah = *(const bf16x8*)(arh + kc * 32 + quad * 8);
        bf16x8 al = *(const bf16x8*)(arl + kc * 32 + quad * 8);
#pragma unroll
        for (int n = 0; n < 12; n++) {
            bf16x8 bfr = *(const bf16x8*)&Ws[n * 16 + l16][kc * 32 + quad * 8];
            acc[n] = __builtin_amdgcn_mfma_f32_16x16x32_bf16(al, bfr, acc[n], 0, 0, 0);
            acc[n] = __builtin_amdgcn_mfma_f32_16x16x32_bf16(ah, bfr, acc[n], 0, 0, 0);
        }
    }

    if (mode == 2) {
#pragma unroll
        for (int reg = 0; reg < 4; reg++) {
            int row = m0 + wrow + quad * 4 + reg;
            int b = row / 784;
            int loc = row - b * 784;
#pragma unroll
            for (int n = 0; n < 12; n++) {
                int col = n * 16 + l16;
                int h = col >> 6, d = col & 63;
                vtbuf[(((size_t)b * 3 + h) * 64 + d) * 784 + loc] = (bf16)acc[n][reg];
            }
        }
    } else {
        bf16* outp = (mode == 0) ? qbuf : kbuf;
        const float s = (mode == 0) ? 0.125f : 1.0f;
#pragma unroll
        for (int reg = 0; reg < 4; reg++) {
            size_t row = m0 + wrow + quad * 4 + reg;
#pragma unroll
            for (int n = 0; n < 12; n++)
                outp[row * 192 + n * 16 + l16] = (bf16)(acc[n][reg] * s);
        }
    }
}

// ---------------------------------------------------------------------------
// Kernel 3: flash attention, S^T formulation, BK=112 (784=7x112).
// ONLY change vs R5: __launch_bounds__(256, 3) — allows ~168 VGPRs, matching
// the LDS-limited 3 blocks/CU, so pf[]/st[] stay in registers (R5's compiler
// heuristic capped at 68 VGPR and spilled pf[] to scratch: 180 MB/dispatch
// of HBM write traffic, WRITE_SIZE 197 MB vs 19 MB legit).
// ---------------------------------------------------------------------------
__global__ __launch_bounds__(256, 3) void attn2_kernel(const bf16* __restrict__ qb,
                                                       const bf16* __restrict__ kb,
                                                       const bf16* __restrict__ vtb,
                                                       float* __restrict__ out) {
    const int LQ = 3136, LK = 784, C = 192;
    int qt = blockIdx.x, h = blockIdx.y, b = blockIdx.z;

    __shared__ bf16 Ks[112][72];    // [key][d]
    __shared__ bf16 Vts[64][136];   // [d][key], cols 112..127 zeroed
    __shared__ bf16 Ps[64][136];    // [q][key],  cols 112..127 zeroed

    int t    = threadIdx.x;
    int lane = t & 63;
    int wid  = t >> 6;
    int l16  = lane & 15;
    int quad = lane >> 4;
    int wrow = wid * 16;

    // zero the key-pad regions once (cols 112..127)
    if (t < 128) {
        int row = t >> 1, part = t & 1;
        *(uint4*)&Ps[row][112 + part * 8] = make_uint4(0u, 0u, 0u, 0u);
    } else {
        int tt = t - 128;
        int row = tt >> 1, part = tt & 1;
        *(uint4*)&Vts[row][112 + part * 8] = make_uint4(0u, 0u, 0u, 0u);
    }

    // Q fragments (B operand: n = q = l16, k = d) held in registers
    bf16x8 qfrag[2];
    {
        const bf16* qrow = qb + ((size_t)b * LQ + qt * 64 + wrow + l16) * C + h * 64;
        qfrag[0] = *(const bf16x8*)(qrow + quad * 8);
        qfrag[1] = *(const bf16x8*)(qrow + 32 + quad * 8);
    }

    const bf16* kbase  = kb + (size_t)b * LK * C + h * 64;
    const bf16* vtbase = vtb + ((size_t)(b * 3 + h)) * 64 * LK;

    // prefetch chunk 0 into registers (1792 uint4 tasks = 7 per thread)
    uint4 pf[7];
#pragma unroll
    for (int i = 0; i < 7; i++) {
        int task = i * 256 + t;
        if (task < 896) {
            int row = task >> 3, s = task & 7;
            pf[i] = *(const uint4*)(kbase + (size_t)row * C + s * 8);
        } else {
            int i2 = task - 896;
            int ck = i2 % 14, d = i2 / 14;
            pf[i] = *(const uint4*)(vtbase + (size_t)d * LK + ck * 8);
        }
    }

    float m_run = -INFINITY, l_run = 0.f;
    f32x4 o_acc[4];
#pragma unroll
    for (int dt = 0; dt < 4; dt++) o_acc[dt] = f32x4{0.f, 0.f, 0.f, 0.f};

    for (int c = 0; c < 7; c++) {
        __syncthreads();   // prior chunk's readers done
        // registers -> LDS
#pragma unroll
        for (int i = 0; i < 7; i++) {
            int task = i * 256 + t;
            if (task < 896) {
                int row = task >> 3, s = task & 7;
                *(uint4*)&Ks[row][s * 8] = pf[i];
            } else {
                int i2 = task - 896;
                int ck = i2 % 14, d = i2 / 14;
                *(uint4*)&Vts[d][ck * 8] = pf[i];
            }
        }
        __syncthreads();
        // issue next chunk's loads (in flight during compute)
        if (c < 6) {
            int j0n = (c + 1) * 112;
#pragma unroll
            for (int i = 0; i < 7; i++) {
                int task = i * 256 + t;
                if (task < 896) {
                    int row = task >> 3, s = task & 7;
                    pf[i] = *(const uint4*)(kbase + (size_t)(j0n + row) * C + s * 8);
                } else {
                    int i2 = task - 896;
                    int ck = i2 % 14, d = i2 / 14;
                    pf[i] = *(const uint4*)(vtbase + (size_t)d * LK + j0n + ck * 8);
                }
            }
        }

        // S^T = K Q^T : 7 key-tiles x (K-dim 64 = 2 steps)
        f32x4 st[7];
#pragma unroll
        for (int kb7 = 0; kb7 < 7; kb7++) st[kb7] = f32x4{0.f, 0.f, 0.f, 0.f};
#pragma unroll
        for (int kk = 0; kk < 2; kk++) {
#pragma unroll
            for (int kb7 = 0; kb7 < 7; kb7++) {
                bf16x8 afrag = *(const bf16x8*)&Ks[kb7 * 16 + l16][kk * 32 + quad * 8];
                st[kb7] = __builtin_amdgcn_mfma_f32_16x16x32_bf16(afrag, qfrag[kk], st[kb7], 0, 0, 0);
            }
        }

        // online softmax for q = l16 (28 keys in-lane, cross-quad shuffles)
        float mx = -INFINITY;
#pragma unroll
        for (int kb7 = 0; kb7 < 7; kb7++)
#pragma unroll
            for (int r = 0; r < 4; r++) mx = fmaxf(mx, st[kb7][r]);
        mx = fmaxf(mx, __shfl_xor(mx, 16, 64));
        mx = fmaxf(mx, __shfl_xor(mx, 32, 64));
        float m_new = fmaxf(m_run, mx);
        float alpha = __expf(m_run - m_new);   // chunk 0: exp(-inf)=0

        float rs = 0.f;
#pragma unroll
        for (int kb7 = 0; kb7 < 7; kb7++) {
            bf16x4 pv;
#pragma unroll
            for (int r = 0; r < 4; r++) {
                float p = __expf(st[kb7][r] - m_new);
                rs += p;
                pv[r] = (bf16)p;
            }
            *(bf16x4*)&Ps[wrow + l16][kb7 * 16 + quad * 4] = pv;
        }
        rs += __shfl_xor(rs, 16, 64);
        rs += __shfl_xor(rs, 32, 64);
        l_run = l_run * alpha + rs;
        m_run = m_new;
#pragma unroll
        for (int dt = 0; dt < 4; dt++)
#pragma unroll
            for (int r = 0; r < 4; r++) o_acc[dt][r] *= alpha;

        // O^T += Vt P^T : keys 128 (16 zero-padded) = 4 steps
#pragma unroll
        for (int kk = 0; kk < 4; kk++) {
            bf16x8 pfrag = *(const bf16x8*)&Ps[wrow + l16][kk * 32 + quad * 8];
#pragma unroll
            for (int dt = 0; dt < 4; dt++) {
                bf16x8 vfrag = *(const bf16x8*)&Vts[dt * 16 + l16][kk * 32 + quad * 8];
                o_acc[dt] = __builtin_amdgcn_mfma_f32_16x16x32_bf16(vfrag, pfrag, o_acc[dt], 0, 0, 0);
            }
        }
    }

    // epilogue: lane holds q = l16, d = dt*16 + quad*4 + reg -> float4 stores
    float invl = 1.f / l_run;
    float* ob = out + ((size_t)b * LQ + qt * 64 + wrow + l16) * C + h * 64;
#pragma unroll
    for (int dt = 0; dt < 4; dt++) {
        float4 v4 = {o_acc[dt][0] * invl, o_acc[dt][1] * invl,
                     o_acc[dt][2] * invl, o_acc[dt][3] * invl};
        *(float4*)(ob + dt * 16 + quad * 4) = v4;
    }
}

// ---------------------------------------------------------------------------
extern "C" void kernel_launch(void* const* d_in, const int* in_sizes, int n_in,
                              void* d_out, int out_size, void* d_ws, size_t ws_size,
                              hipStream_t stream) {
    const float* x = (const float*)d_in[0];

    const float* q_dw = (const float*)d_in[1];
    const float* q_scale = (const float*)d_in[2];
    const float* q_bias = (const float*)d_in[3];
    const float* q_mean = (const float*)d_in[4];
    const float* q_var = (const float*)d_in[5];
    const float* q_pw = (const float*)d_in[6];

    const float* k_dw = (const float*)d_in[7];
    const float* k_scale = (const float*)d_in[8];
    const float* k_bias = (const float*)d_in[9];
    const float* k_mean = (const float*)d_in[10];
    const float* k_var = (const float*)d_in[11];
    const float* k_pw = (const float*)d_in[12];

    const float* v_dw = (const float*)d_in[13];
    const float* v_scale = (const float*)d_in[14];
    const float* v_bias = (const float*)d_in[15];
    const float* v_mean = (const float*)d_in[16];
    const float* v_var = (const float*)d_in[17];
    const float* v_pw = (const float*)d_in[18];

    float* out = (float*)d_out;

    // workspace layout (bytes, all 16B aligned)
    char* ws = (char*)d_ws;
    bf16* qhi = (bf16*)(ws);                  // 9,633,792
    bf16* qlo = (bf16*)(ws + 9633792);        // 9,633,792
    bf16* khi = (bf16*)(ws + 19267584);       // 2,408,448
    bf16* klo = (bf16*)(ws + 21676032);       // 2,408,448
    bf16* vhi = (bf16*)(ws + 24084480);       // 2,408,448
    bf16* vlo = (bf16*)(ws + 26492928);       // 2,408,448
    bf16* qbuf = (bf16*)(ws + 28901376);      // 9,633,792
    bf16* kbuf = (bf16*)(ws + 38535168);      // 2,408,448
    bf16* vtbuf = (bf16*)(ws + 40943616);     // 2,408,448
    bf16* wt = (bf16*)(ws + 43352064);        // 221,184

    // stage 1: conv(Q) + conv(K,V) + weight cast, one launch (6312 blocks)
    conv_all_kernel<<<6312, 256, 0, stream>>>(
        x,
        q_dw, q_scale, q_bias, q_mean, q_var,
        k_dw, k_scale, k_bias, k_mean, k_var,
        v_dw, v_scale, v_bias, v_mean, v_var,
        q_pw, k_pw, v_pw,
        qhi, qlo, khi, klo, vhi, vlo, wt);

    // stage 2: all three pointwise GEMMs, one launch (588 blocks)
    gemm_all_kernel<<<588, 256, 0, stream>>>(
        qhi, qlo, khi, klo, vhi, vlo, wt, qbuf, kbuf, vtbuf);

    // stage 3: attention (49 q-tiles, 3 heads, 8 batches)
    attn2_kernel<<<dim3(49, 3, 8), 256, 0, stream>>>(qbuf, kbuf, vtbuf, out);
}

// Round 7
// 187.076 us; speedup vs baseline: 3.2927x; 1.2140x over previous
//
#include <hip/hip_runtime.h>
#include <cmath>

#define EPS_BN 1e-5f

typedef __bf16 bf16;
typedef __bf16 bf16x4 __attribute__((ext_vector_type(4)));
typedef __bf16 bf16x8 __attribute__((ext_vector_type(8)));
typedef float  f32x4  __attribute__((ext_vector_type(4)));

// async global->LDS DMA, 16 B per lane, LDS dest = wave-uniform base + lane*16
__device__ __forceinline__ void dma16(const bf16* g, bf16* l) {
    __builtin_amdgcn_global_load_lds(
        (const __attribute__((address_space(1))) void*)g,
        (__attribute__((address_space(3))) void*)l, 16, 0, 0);
}

// ---------------------------------------------------------------------------
// Kernel 1: all preprocessing elementwise work in one launch. (unchanged R6)
// ---------------------------------------------------------------------------
__global__ __launch_bounds__(256) void conv_all_kernel(
    const float* __restrict__ x,
    const float* __restrict__ qdw, const float* __restrict__ qscale,
    const float* __restrict__ qbias, const float* __restrict__ qmean,
    const float* __restrict__ qvar,
    const float* __restrict__ kdw, const float* __restrict__ kscale,
    const float* __restrict__ kbias, const float* __restrict__ kmean,
    const float* __restrict__ kvar,
    const float* __restrict__ vdw, const float* __restrict__ vscale,
    const float* __restrict__ vbias, const float* __restrict__ vmean,
    const float* __restrict__ vvar,
    const float* __restrict__ qpw, const float* __restrict__ kpw,
    const float* __restrict__ vpw,
    bf16* __restrict__ qhi, bf16* __restrict__ qlo,
    bf16* __restrict__ khi, bf16* __restrict__ klo,
    bf16* __restrict__ vhi, bf16* __restrict__ vlo,
    bf16* __restrict__ wt) {
    const int WW = 56, C = 192;
    int bid = blockIdx.x;

    if (bid < 4704) {
        int idx = bid * 256 + threadIdx.x;
        int p  = idx / 48;
        int c4 = (idx - p * 48) * 4;
        int b  = p / 3136;
        int rem = p - b * 3136;
        int oy = rem / 56;
        int ox = rem - oy * 56;
        const float* xb = x + (size_t)b * 3136 * C;

        float4 sc = *(const float4*)&qscale[c4];
        float4 vr = *(const float4*)&qvar[c4];
        float4 bi = *(const float4*)&qbias[c4];
        float4 mn = *(const float4*)&qmean[c4];
        float aA[4] = {sc.x * rsqrtf(vr.x + EPS_BN), sc.y * rsqrtf(vr.y + EPS_BN),
                       sc.z * rsqrtf(vr.z + EPS_BN), sc.w * rsqrtf(vr.w + EPS_BN)};
        float aB[4] = {bi.x - mn.x * aA[0], bi.y - mn.y * aA[1],
                       bi.z - mn.z * aA[2], bi.w - mn.w * aA[3]};
        float s[4] = {0.f, 0.f, 0.f, 0.f};
#pragma unroll
        for (int ky = 0; ky < 3; ky++) {
            int iy = oy + ky - 1;
            bool yok = (iy >= 0) && (iy < 56);
#pragma unroll
            for (int kx = 0; kx < 3; kx++) {
                int ix = ox + kx - 1;
                if (yok && ix >= 0 && ix < WW) {
                    float4 xv = *(const float4*)&xb[((size_t)iy * WW + ix) * C + c4];
                    float4 wv = *(const float4*)&qdw[(ky * 3 + kx) * C + c4];
                    s[0] += xv.x * wv.x; s[1] += xv.y * wv.y;
                    s[2] += xv.z * wv.z; s[3] += xv.w * wv.w;
                }
            }
        }
        bf16x4 hv, lv;
#pragma unroll
        for (int j = 0; j < 4; j++) {
            float av = s[j] * aA[j] + aB[j];
            bf16 hh = (bf16)av;
            hv[j] = hh;
            lv[j] = (bf16)(av - (float)hh);
        }
        *(bf16x4*)&qhi[(size_t)p * C + c4] = hv;
        *(bf16x4*)&qlo[(size_t)p * C + c4] = lv;
    } else if (bid < 5880) {
        int idx = (bid - 4704) * 256 + threadIdx.x;
        int p  = idx / 48;
        int c4 = (idx - p * 48) * 4;
        int b  = p / 784;
        int rem = p - b * 784;
        int oy = rem / 28;
        int ox = rem - oy * 28;
        const float* xb = x + (size_t)b * 3136 * C;

        float ks[4] = {0.f, 0.f, 0.f, 0.f};
        float vs[4] = {0.f, 0.f, 0.f, 0.f};
#pragma unroll
        for (int ky = 0; ky < 3; ky++) {
            int iy = oy * 2 + ky;
            bool yok = iy < 56;
#pragma unroll
            for (int kx = 0; kx < 3; kx++) {
                int ix = ox * 2 + kx;
                if (yok && ix < WW) {
                    float4 xv = *(const float4*)&xb[((size_t)iy * WW + ix) * C + c4];
                    float4 kw = *(const float4*)&kdw[(ky * 3 + kx) * C + c4];
                    float4 vw = *(const float4*)&vdw[(ky * 3 + kx) * C + c4];
                    ks[0] += xv.x * kw.x; ks[1] += xv.y * kw.y;
                    ks[2] += xv.z * kw.z; ks[3] += xv.w * kw.w;
                    vs[0] += xv.x * vw.x; vs[1] += xv.y * vw.y;
                    vs[2] += xv.z * vw.z; vs[3] += xv.w * vw.w;
                }
            }
        }
        float4 ksc = *(const float4*)&kscale[c4];
        float4 kvr = *(const float4*)&kvar[c4];
        float4 kbi = *(const float4*)&kbias[c4];
        float4 kmn = *(const float4*)&kmean[c4];
        float4 vsc = *(const float4*)&vscale[c4];
        float4 vvr = *(const float4*)&vvar[c4];
        float4 vbi = *(const float4*)&vbias[c4];
        float4 vmn = *(const float4*)&vmean[c4];
        float kA[4] = {ksc.x * rsqrtf(kvr.x + EPS_BN), ksc.y * rsqrtf(kvr.y + EPS_BN),
                       ksc.z * rsqrtf(kvr.z + EPS_BN), ksc.w * rsqrtf(kvr.w + EPS_BN)};
        float kB[4] = {kbi.x - kmn.x * kA[0], kbi.y - kmn.y * kA[1],
                       kbi.z - kmn.z * kA[2], kbi.w - kmn.w * kA[3]};
        float vA[4] = {vsc.x * rsqrtf(vvr.x + EPS_BN), vsc.y * rsqrtf(vvr.y + EPS_BN),
                       vsc.z * rsqrtf(vvr.z + EPS_BN), vsc.w * rsqrtf(vvr.w + EPS_BN)};
        float vB[4] = {vbi.x - vmn.x * vA[0], vbi.y - vmn.y * vA[1],
                       vbi.z - vmn.z * vA[2], vbi.w - vmn.w * vA[3]};
        bf16x4 kh, kl, vh, vl;
#pragma unroll
        for (int j = 0; j < 4; j++) {
            float kf = ks[j] * kA[j] + kB[j];
            float vf = vs[j] * vA[j] + vB[j];
            bf16 h1 = (bf16)kf; kh[j] = h1; kl[j] = (bf16)(kf - (float)h1);
            bf16 h2 = (bf16)vf; vh[j] = h2; vl[j] = (bf16)(vf - (float)h2);
        }
        *(bf16x4*)&khi[(size_t)p * C + c4] = kh;
        *(bf16x4*)&klo[(size_t)p * C + c4] = kl;
        *(bf16x4*)&vhi[(size_t)p * C + c4] = vh;
        *(bf16x4*)&vlo[(size_t)p * C + c4] = vl;
    } else {
        int idx = (bid - 5880) * 256 + threadIdx.x;
        if (idx < 3 * 36864) {
            int mat = idx / 36864, r = idx % 36864;
            int n = r / 192, k = r - n * 192;
            const float* src = (mat == 0) ? qpw : (mat == 1) ? kpw : vpw;
            wt[idx] = (bf16)src[k * 192 + n];
        }
    }
}

// ---------------------------------------------------------------------------
// Kernel 2: all three pointwise GEMMs in one launch. (unchanged R6)
// ---------------------------------------------------------------------------
__global__ __launch_bounds__(256) void gemm_all_kernel(
    const bf16* __restrict__ qhi, const bf16* __restrict__ qlo,
    const bf16* __restrict__ khi, const bf16* __restrict__ klo,
    const bf16* __restrict__ vhi, const bf16* __restrict__ vlo,
    const bf16* __restrict__ wt,
    bf16* __restrict__ qbuf, bf16* __restrict__ kbuf, bf16* __restrict__ vtbuf) {
    __shared__ bf16 Ws[192][200];
    int t = threadIdx.x;
    int bid = blockIdx.x;

    int mode, mt;
    const bf16 *Ahi, *Alo, *Wsrc;
    if (bid < 392)      { mode = 0; mt = bid;       Ahi = qhi; Alo = qlo; Wsrc = wt; }
    else if (bid < 490) { mode = 1; mt = bid - 392; Ahi = khi; Alo = klo; Wsrc = wt + 36864; }
    else                { mode = 2; mt = bid - 490; Ahi = vhi; Alo = vlo; Wsrc = wt + 73728; }

#pragma unroll
    for (int it = 0; it < 18; it++) {
        int idx = it * 256 + t;
        int n = idx / 24, ck = idx - n * 24;
        *(uint4*)&Ws[n][ck * 8] = *(const uint4*)&Wsrc[n * 192 + ck * 8];
    }
    __syncthreads();

    int lane = t & 63, wid = t >> 6;
    int l16 = lane & 15, quad = lane >> 4;
    int wrow = wid * 16;
    int m0 = mt * 64;

    f32x4 acc[12];
#pragma unroll
    for (int n = 0; n < 12; n++) acc[n] = f32x4{0.f, 0.f, 0.f, 0.f};

    const bf16* arh = Ahi + (size_t)(m0 + wrow + l16) * 192;
    const bf16* arl = Alo + (size_t)(m0 + wrow + l16) * 192;
#pragma unroll
    for (int kc = 0; kc < 6; kc++) {
        bf16x8 ah = *(const bf16x8*)(arh + kc * 32 + quad * 8);
        bf16x8 al = *(const bf16x8*)(arl + kc * 32 + quad * 8);
#pragma unroll
        for (int n = 0; n < 12; n++) {
            bf16x8 bfr = *(const bf16x8*)&Ws[n * 16 + l16][kc * 32 + quad * 8];
            acc[n] = __builtin_amdgcn_mfma_f32_16x16x32_bf16(al, bfr, acc[n], 0, 0, 0);
            acc[n] = __builtin_amdgcn_mfma_f32_16x16x32_bf16(ah, bfr, acc[n], 0, 0, 0);
        }
    }

    if (mode == 2) {
#pragma unroll
        for (int reg = 0; reg < 4; reg++) {
            int row = m0 + wrow + quad * 4 + reg;
            int b = row / 784;
            int loc = row - b * 784;
#pragma unroll
            for (int n = 0; n < 12; n++) {
                int col = n * 16 + l16;
                int h = col >> 6, d = col & 63;
                vtbuf[(((size_t)b * 3 + h) * 64 + d) * 784 + loc] = (bf16)acc[n][reg];
            }
        }
    } else {
        bf16* outp = (mode == 0) ? qbuf : kbuf;
        const float s = (mode == 0) ? 0.125f : 1.0f;
#pragma unroll
        for (int reg = 0; reg < 4; reg++) {
            size_t row = m0 + wrow + quad * 4 + reg;
#pragma unroll
            for (int n = 0; n < 12; n++)
                outp[row * 192 + n * 16 + l16] = (bf16)(acc[n][reg] * s);
        }
    }
}

// ---------------------------------------------------------------------------
// Kernel 3: flash attention, S^T formulation, BK=112, async-DMA staging.
// K/V staged via global_load_lds (no staging VGPRs -> nothing to spill).
// Padded LDS rows expressed as flat 1024-B wave stripes:
//   Ks: 112 rows x (8 data + 1 pad) 16B-chunks = 1008 chunks -> 16 stripes
//       (+256 B tail guard for the final stripe's overshoot)
//   Vts: 64 rows x 17 chunks (14 data + 2 key-pad + 1 row-pad) = 17 stripes
// Pad chunks receive finite garbage; key-pad cols of Vt multiply against
// Ps pad cols, which are zeroed once and never rewritten.
// amdgpu_waves_per_eu(3,3): allocator budget ~170 VGPR (LDS already caps
// occupancy at 3 blocks/CU, so nothing is lost).
// ---------------------------------------------------------------------------
__global__ __launch_bounds__(256)
__attribute__((amdgpu_waves_per_eu(3, 3)))
void attn3_kernel(const bf16* __restrict__ qb,
                  const bf16* __restrict__ kb,
                  const bf16* __restrict__ vtb,
                  float* __restrict__ out) {
    const int LQ = 3136, LK = 784, C = 192;
    int qt = blockIdx.x, h = blockIdx.y, b = blockIdx.z;

    __shared__ bf16 Ks[8192];       // [key][72] flat, 112 rows + 256B tail guard
    __shared__ bf16 Vts[64][136];   // [d][key], keys 112..127 garbage (x Ps zeros)
    __shared__ bf16 Ps[64][136];    // [q][key], cols 112..127 zeroed once

    int t    = threadIdx.x;
    int lane = t & 63;
    int wid  = t >> 6;
    int l16  = lane & 15;
    int quad = lane >> 4;
    int wrow = wid * 16;

    // zero Ps pad cols once (these annihilate Vt garbage in the PV MFMA)
    if (t < 128) {
        int row = t >> 1, part = t & 1;
        *(uint4*)&Ps[row][112 + part * 8] = make_uint4(0u, 0u, 0u, 0u);
    }

    // Q fragments (B operand: n = q = l16, k = d) held in registers
    bf16x8 qfrag[2];
    {
        const bf16* qrow = qb + ((size_t)b * LQ + qt * 64 + wrow + l16) * C + h * 64;
        qfrag[0] = *(const bf16x8*)(qrow + quad * 8);
        qfrag[1] = *(const bf16x8*)(qrow + 32 + quad * 8);
    }

    const bf16* kbase  = kb + (size_t)b * LK * C + h * 64;
    const bf16* vtbase = vtb + ((size_t)(b * 3 + h)) * 64 * LK;

    float m_run = -INFINITY, l_run = 0.f;
    f32x4 o_acc[4];
#pragma unroll
    for (int dt = 0; dt < 4; dt++) o_acc[dt] = f32x4{0.f, 0.f, 0.f, 0.f};

    for (int c = 0; c < 7; c++) {
        int j0 = c * 112;
        __syncthreads();   // prior chunk's LDS readers done (c=0: pad zeros done)

        // issue async DMA: 33 stripes round-robined over 4 waves
        for (int s = wid; s < 33; s += 4) {
            if (s < 16) {
                int j = s * 64 + lane;         // chunk index into Ks (9 per row)
                int r = j / 9, cc = j - r * 9;
                const bf16* src = (cc < 8 && r < 112)
                                  ? kbase + (size_t)(j0 + r) * C + cc * 8
                                  : kbase;     // finite garbage into pads
                dma16(src, &Ks[s * 512]);
            } else {
                int s2 = s - 16;
                int j = s2 * 64 + lane;        // chunk index into Vts (17 per row)
                int r = j / 17, cc = j - r * 17;
                const bf16* src = (cc < 14)
                                  ? vtbase + (size_t)r * LK + j0 + cc * 8
                                  : vtbase;    // finite garbage into pads
                dma16(src, (bf16*)Vts + s2 * 512);
            }
        }
        __syncthreads();   // drains vmcnt before barrier -> DMA data visible

        // S^T = K Q^T : 7 key-tiles x (K-dim 64 = 2 steps)
        f32x4 st[7];
#pragma unroll
        for (int kb7 = 0; kb7 < 7; kb7++) st[kb7] = f32x4{0.f, 0.f, 0.f, 0.f};
#pragma unroll
        for (int kk = 0; kk < 2; kk++) {
#pragma unroll
            for (int kb7 = 0; kb7 < 7; kb7++) {
                bf16x8 afrag = *(const bf16x8*)&Ks[(kb7 * 16 + l16) * 72 + kk * 32 + quad * 8];
                st[kb7] = __builtin_amdgcn_mfma_f32_16x16x32_bf16(afrag, qfrag[kk], st[kb7], 0, 0, 0);
            }
        }

        // online softmax for q = l16 (28 keys in-lane, cross-quad shuffles)
        float mx = -INFINITY;
#pragma unroll
        for (int kb7 = 0; kb7 < 7; kb7++)
#pragma unroll
            for (int r = 0; r < 4; r++) mx = fmaxf(mx, st[kb7][r]);
        mx = fmaxf(mx, __shfl_xor(mx, 16, 64));
        mx = fmaxf(mx, __shfl_xor(mx, 32, 64));
        float m_new = fmaxf(m_run, mx);
        float alpha = __expf(m_run - m_new);   // chunk 0: exp(-inf)=0

        float rs = 0.f;
#pragma unroll
        for (int kb7 = 0; kb7 < 7; kb7++) {
            bf16x4 pv;
#pragma unroll
            for (int r = 0; r < 4; r++) {
                float p = __expf(st[kb7][r] - m_new);
                rs += p;
                pv[r] = (bf16)p;
            }
            *(bf16x4*)&Ps[wrow + l16][kb7 * 16 + quad * 4] = pv;
        }
        rs += __shfl_xor(rs, 16, 64);
        rs += __shfl_xor(rs, 32, 64);
        l_run = l_run * alpha + rs;
        m_run = m_new;
#pragma unroll
        for (int dt = 0; dt < 4; dt++)
#pragma unroll
            for (int r = 0; r < 4; r++) o_acc[dt][r] *= alpha;

        // O^T += Vt P^T : keys 128 (16 zero-P-padded) = 4 steps
#pragma unroll
        for (int kk = 0; kk < 4; kk++) {
            bf16x8 pfrag = *(const bf16x8*)&Ps[wrow + l16][kk * 32 + quad * 8];
#pragma unroll
            for (int dt = 0; dt < 4; dt++) {
                bf16x8 vfrag = *(const bf16x8*)&Vts[dt * 16 + l16][kk * 32 + quad * 8];
                o_acc[dt] = __builtin_amdgcn_mfma_f32_16x16x32_bf16(vfrag, pfrag, o_acc[dt], 0, 0, 0);
            }
        }
    }

    // epilogue: lane holds q = l16, d = dt*16 + quad*4 + reg -> float4 stores
    float invl = 1.f / l_run;
    float* ob = out + ((size_t)b * LQ + qt * 64 + wrow + l16) * C + h * 64;
#pragma unroll
    for (int dt = 0; dt < 4; dt++) {
        float4 v4 = {o_acc[dt][0] * invl, o_acc[dt][1] * invl,
                     o_acc[dt][2] * invl, o_acc[dt][3] * invl};
        *(float4*)(ob + dt * 16 + quad * 4) = v4;
    }
}

// ---------------------------------------------------------------------------
extern "C" void kernel_launch(void* const* d_in, const int* in_sizes, int n_in,
                              void* d_out, int out_size, void* d_ws, size_t ws_size,
                              hipStream_t stream) {
    const float* x = (const float*)d_in[0];

    const float* q_dw = (const float*)d_in[1];
    const float* q_scale = (const float*)d_in[2];
    const float* q_bias = (const float*)d_in[3];
    const float* q_mean = (const float*)d_in[4];
    const float* q_var = (const float*)d_in[5];
    const float* q_pw = (const float*)d_in[6];

    const float* k_dw = (const float*)d_in[7];
    const float* k_scale = (const float*)d_in[8];
    const float* k_bias = (const float*)d_in[9];
    const float* k_mean = (const float*)d_in[10];
    const float* k_var = (const float*)d_in[11];
    const float* k_pw = (const float*)d_in[12];

    const float* v_dw = (const float*)d_in[13];
    const float* v_scale = (const float*)d_in[14];
    const float* v_bias = (const float*)d_in[15];
    const float* v_mean = (const float*)d_in[16];
    const float* v_var = (const float*)d_in[17];
    const float* v_pw = (const float*)d_in[18];

    float* out = (float*)d_out;

    // workspace layout (bytes, all 16B aligned)
    char* ws = (char*)d_ws;
    bf16* qhi = (bf16*)(ws);                  // 9,633,792
    bf16* qlo = (bf16*)(ws + 9633792);        // 9,633,792
    bf16* khi = (bf16*)(ws + 19267584);       // 2,408,448
    bf16* klo = (bf16*)(ws + 21676032);       // 2,408,448
    bf16* vhi = (bf16*)(ws + 24084480);       // 2,408,448
    bf16* vlo = (bf16*)(ws + 26492928);       // 2,408,448
    bf16* qbuf = (bf16*)(ws + 28901376);      // 9,633,792
    bf16* kbuf = (bf16*)(ws + 38535168);      // 2,408,448
    bf16* vtbuf = (bf16*)(ws + 40943616);     // 2,408,448
    bf16* wt = (bf16*)(ws + 43352064);        // 221,184

    // stage 1: conv(Q) + conv(K,V) + weight cast, one launch (6312 blocks)
    conv_all_kernel<<<6312, 256, 0, stream>>>(
        x,
        q_dw, q_scale, q_bias, q_mean, q_var,
        k_dw, k_scale, k_bias, k_mean, k_var,
        v_dw, v_scale, v_bias, v_mean, v_var,
        q_pw, k_pw, v_pw,
        qhi, qlo, khi, klo, vhi, vlo, wt);

    // stage 2: all three pointwise GEMMs, one launch (588 blocks)
    gemm_all_kernel<<<588, 256, 0, stream>>>(
        qhi, qlo, khi, klo, vhi, vlo, wt, qbuf, kbuf, vtbuf);

    // stage 3: attention (49 q-tiles, 3 heads, 8 batches)
    attn3_kernel<<<dim3(49, 3, 8), 256, 0, stream>>>(qbuf, kbuf, vtbuf, out);
}